// Round 10
// baseline (1227.048 us; speedup 1.0000x reference)
//
#include <hip/hip_runtime.h>
#include <hip/hip_bf16.h>

typedef unsigned short u16;
typedef unsigned int   u32;

#define BB   2
#define NN   2048
#define HS   16
#define DH   64
#define NM   16
#define JT   2064   // NM + NN
#define DIM  1024
#define JC   5      // partial top-8 slots per row (max blocks covering a row)
#define NBB  256    // blocks per batch (b)
#define TOTT 8384   // total j-tiles per batch: sum_{iy}(iy+2)

#define SPLITSZ ((size_t)BB * HS * JT * DH)   // elements per K-split plane

__device__ __forceinline__ float bfval(u16 u) { return __uint_as_float(((u32)u) << 16); }
__device__ __forceinline__ float lo16(u32 u)  { return __uint_as_float(u << 16); }
__device__ __forceinline__ float hi16(u32 u)  { return __uint_as_float(u & 0xffff0000u); }
__device__ __forceinline__ u16 f2bf(float f)
{
    __hip_bfloat16 h = __float2bfloat16(f);
    return *(u16*)&h;
}

// tile-space partition: block k (k=0..255 per b) owns tiles [start(k), start(k+1))
// start(k) = floor(131k/4)  (TOTT/NBB = 32.75 = 131/4, exact)
__device__ __forceinline__ int blk_start(int k) { return (131 * k) >> 2; }
__device__ __forceinline__ int blk_of(int g)
{
    int k = (4 * g) / 131;
    while (blk_start(k + 1) <= g) ++k;
    while (blk_start(k) > g) --k;
    return k;
}
// row (iy) starts at tile S(iy) = iy*(iy+3)/2
__device__ __forceinline__ int row_start(int iy) { return (iy * (iy + 3)) >> 1; }

typedef __bf16 bf16x8 __attribute__((ext_vector_type(8)));
typedef float  f32x4  __attribute__((ext_vector_type(4)));

#define MFMA16(A, B, C) __builtin_amdgcn_mfma_f32_16x16x32_bf16(A, B, C, 0, 0, 0)

// ---------------------------------------------------------------------------
// mem_k rows -> K-split planes (hi/mid/lo bf16) at key rows 0..15.
// ---------------------------------------------------------------------------
__global__ void prep_mem_kernel(const float* __restrict__ mem_k, u16* __restrict__ k_sp)
{
    int t = blockIdx.x * 256 + threadIdx.x;          // 0 .. 32767
    int d = t & 63, j = (t >> 6) & 15, h = (t >> 10) & 15, b = (t >> 14) & 1;
    float x = mem_k[(h * NM + j) * DH + d];
    size_t di = ((size_t)(b * HS + h) * JT + j) * DH + d;
    u16 sh = f2bf(x);
    float d1 = x - bfval(sh);
    u16 sm = f2bf(d1);
    u16 sl = f2bf(d1 - bfval(sm));
    k_sp[di] = sh; k_sp[di + SPLITSZ] = sm; k_sp[di + 2 * SPLITSZ] = sl;
}

// ---------------------------------------------------------------------------
// Wo f32 [k][n] -> WoT bf16 [n][k] (B-frag native layout for the epilogue).
// ---------------------------------------------------------------------------
__global__ void prep_wot_kernel(const float* __restrict__ Wo, u16* __restrict__ wot)
{
    int t = blockIdx.x * 256 + threadIdx.x;          // 0 .. 1048575
    int k = t & 1023, n = t >> 10;
    wot[(size_t)n * 1024 + k] = f2bf(Wo[(size_t)k * 1024 + n]);
}

// ---------------------------------------------------------------------------
// Exact-f32 GEMM via bf16 split MFMA (core verified R7-R9).
// mode 0: V -> bf16 scatter. R18: 4-pass (mm,hm,mh,hh) — dropped hl/lh terms
//         are O(2^-16) relative, two orders below V's own bf16 rounding.
// mode 1: Q -> f32 row-major (6-pass exact: feeds score top-k, keep).
// mode 2: K -> hi/mid/lo split planes (6-pass exact).
// ---------------------------------------------------------------------------
__global__ __launch_bounds__(256) void gemm_kernel(
    const float* __restrict__ A, const float* __restrict__ Bw,
    u16* __restrict__ dst16, float* __restrict__ dstf, int mode)
{
    __shared__ __align__(16) u16 a_h[128][32];
    __shared__ __align__(16) u16 a_m[128][32];
    __shared__ __align__(16) u16 a_l[128][32];
    __shared__ __align__(16) u16 b_hT[64][32];
    __shared__ __align__(16) u16 b_mT[64][32];
    __shared__ __align__(16) u16 b_lT[64][32];

    const int tid  = threadIdx.x;
    const int m0   = blockIdx.x * 128;
    const int n0   = blockIdx.y * 64;
    const int wave = tid >> 6, lane = tid & 63;
    const int ln16 = lane & 15, quad = lane >> 4;

    const int arow = tid >> 1;            // 0..127
    const int ac   = (tid & 1) * 16;      // 0 or 16
    const int brow = tid >> 3;            // 0..31
    const int bc   = (tid & 7) * 8;       // 0..56

    f32x4 acc[8] = {};

    for (int k0 = 0; k0 < 1024; k0 += 32) {
        float av[16];
        {
            const float4* ap = (const float4*)&A[(size_t)(m0 + arow) * 1024 + k0 + ac];
            *(float4*)&av[0]  = ap[0]; *(float4*)&av[4]  = ap[1];
            *(float4*)&av[8]  = ap[2]; *(float4*)&av[12] = ap[3];
        }
        float bv[8];
        {
            const float4* bp = (const float4*)&Bw[(size_t)(k0 + brow) * 1024 + n0 + bc];
            *(float4*)&bv[0] = bp[0]; *(float4*)&bv[4] = bp[1];
        }
        u16 ah[16], am[16], al[16], bh[8], bm[8], bl[8];
        #pragma unroll
        for (int e = 0; e < 16; ++e) {
            ah[e] = f2bf(av[e]);
            float d1 = av[e] - bfval(ah[e]);
            am[e] = f2bf(d1);
            al[e] = (mode != 0) ? f2bf(d1 - bfval(am[e])) : (u16)0;
        }
        #pragma unroll
        for (int e = 0; e < 8; ++e) {
            bh[e] = f2bf(bv[e]);
            float d1 = bv[e] - bfval(bh[e]);
            bm[e] = f2bf(d1);
            bl[e] = (mode != 0) ? f2bf(d1 - bfval(bm[e])) : (u16)0;
        }
        __syncthreads();
        *(uint4*)&a_h[arow][ac]     = ((uint4*)ah)[0];
        *(uint4*)&a_h[arow][ac + 8] = ((uint4*)ah)[1];
        *(uint4*)&a_m[arow][ac]     = ((uint4*)am)[0];
        *(uint4*)&a_m[arow][ac + 8] = ((uint4*)am)[1];
        if (mode != 0) {
            *(uint4*)&a_l[arow][ac]     = ((uint4*)al)[0];
            *(uint4*)&a_l[arow][ac + 8] = ((uint4*)al)[1];
        }
        #pragma unroll
        for (int e = 0; e < 8; ++e) {
            b_hT[bc + e][brow] = bh[e];
            b_mT[bc + e][brow] = bm[e];
            if (mode != 0) b_lT[bc + e][brow] = bl[e];
        }
        __syncthreads();

        bf16x8 a0h = *(const bf16x8*)&a_h[wave * 32 + ln16][quad * 8];
        bf16x8 a0m = *(const bf16x8*)&a_m[wave * 32 + ln16][quad * 8];
        bf16x8 a1h = *(const bf16x8*)&a_h[wave * 32 + 16 + ln16][quad * 8];
        bf16x8 a1m = *(const bf16x8*)&a_m[wave * 32 + 16 + ln16][quad * 8];
        bf16x8 a0l = {}, a1l = {};
        if (mode != 0) {
            a0l = *(const bf16x8*)&a_l[wave * 32 + ln16][quad * 8];
            a1l = *(const bf16x8*)&a_l[wave * 32 + 16 + ln16][quad * 8];
        }
        #pragma unroll
        for (int c = 0; c < 4; ++c) {
            bf16x8 bh_ = *(const bf16x8*)&b_hT[c * 16 + ln16][quad * 8];
            bf16x8 bm_ = *(const bf16x8*)&b_mT[c * 16 + ln16][quad * 8];
            acc[c]     = MFMA16(a0m, bm_, acc[c]);
            acc[c]     = MFMA16(a0h, bm_, acc[c]);
            acc[c]     = MFMA16(a0m, bh_, acc[c]);
            acc[c]     = MFMA16(a0h, bh_, acc[c]);
            acc[4 + c] = MFMA16(a1m, bm_, acc[4 + c]);
            acc[4 + c] = MFMA16(a1h, bm_, acc[4 + c]);
            acc[4 + c] = MFMA16(a1m, bh_, acc[4 + c]);
            acc[4 + c] = MFMA16(a1h, bh_, acc[4 + c]);
            if (mode != 0) {
                bf16x8 bl_ = *(const bf16x8*)&b_lT[c * 16 + ln16][quad * 8];
                acc[c]     = MFMA16(a0h, bl_, acc[c]);
                acc[c]     = MFMA16(a0l, bh_, acc[c]);
                acc[4 + c] = MFMA16(a1h, bl_, acc[4 + c]);
                acc[4 + c] = MFMA16(a1l, bh_, acc[4 + c]);
            }
        }
    }

    #pragma unroll
    for (int hf = 0; hf < 2; ++hf) {
        #pragma unroll
        for (int c = 0; c < 4; ++c) {
            #pragma unroll
            for (int r = 0; r < 4; ++r) {
                int row = m0 + wave * 32 + hf * 16 + quad * 4 + r;
                int col = n0 + c * 16 + ln16;
                float v = acc[hf * 4 + c][r];
                if (mode == 1) {
                    dstf[(size_t)row * 1024 + col] = v;
                } else {
                    int b = row >> 11, i = row & 2047;
                    int hd = col >> 6, d = col & 63;
                    if (mode == 0) {
                        dst16[(((size_t)(b * HS + hd)) * NN + i) * DH + d] = f2bf(v);
                    } else {
                        size_t di = (((size_t)(b * HS + hd)) * JT + NM + i) * DH + d;
                        u16 sh = f2bf(v);
                        float d1 = v - bfval(sh);
                        u16 sm = f2bf(d1);
                        u16 sl = f2bf(d1 - bfval(sm));
                        dst16[di] = sh;
                        dst16[di + SPLITSZ] = sm;
                        dst16[di + 2 * SPLITSZ] = sl;
                    }
                }
            }
        }
    }
}

// ---------------------------------------------------------------------------
// Phase 1 (MFMA): scores + partial top-8.
// R19 == R18 (resubmission after infra failure; audited for hang/OOB):
//  all 12 K loads (2 heads x 2 halves x 3 planes) for the NEXT tile are
//  issued after this tile's MFMAs and stay in flight across barrier+mix.
//  K addresses depend only on jt (not iy), so jt_next = (jt+1<jt_hi) ?
//  jt+1 : 0 pipelines ACROSS row boundaries — no per-row drain.
//  __launch_bounds__(512,4) caps VGPR at 128 (4 waves/EU) so a pressure
//  miss can't halve occupancy; est. natural pressure ~112-122.
// ---------------------------------------------------------------------------
__global__ __launch_bounds__(512, 4) void score_topk_kernel(
    const u16* __restrict__ k_hi, const u16* __restrict__ k_mi,
    const u16* __restrict__ k_lo,
    const float* __restrict__ q_all, const float* __restrict__ pre,
    float* __restrict__ ws_val, u16* __restrict__ ws_idx)
{
    const int bid = blockIdx.x;                  // 0..511
    const int b   = bid >> 8;
    const int kb  = bid & 255;                   // striped: XCD = kb % 8

    int g = blk_start(kb);
    const int gend = blk_start(kb + 1);

    __shared__ __align__(16) float fsm[12544];
    float* S   = fsm;            // [2][16][256] dbuf, chunk-rotation swizzled
    float* pp  = fsm + 8192;     // [256] pre_proj * 0.125
    float* scr = fsm + 8448;     // [4096] row-flush merge scratch

    const int tid  = threadIdx.x;
    const int wave = tid >> 6, lane = tid & 63;
    const int ln16 = lane & 15, quad = lane >> 4;

    if (tid < 256) pp[tid] = pre[tid] * 0.125f;
    __syncthreads();                             // pp staged

    // scan-row ownership: waves 0-3 scan tj-half 0, waves 4-7 tj-half 1
    const int kk_r = (wave & 3) * 4 + (lane & 3);
    const int ti_r = lane >> 2;
    const int tjh  = wave >> 2;
    const int srow = kk_r * 16 + ti_r;           // scratch row id

    // u32 element offset base for this thread's K-row slice (b, lane row)
    const u32 kbase0 = ((u32)(b * HS) * JT + (u32)ln16) * DH + (u32)(quad * 8);
    const u32 hstep  = (u32)(JT * DH);           // head stride in elements
    const u32 kbA    = kbase0 + (u32)(wave * 2) * hstep;       // head wave*2
    const u32 kbB    = kbA + hstep;                            // head wave*2+1

    // initial row: largest iy with row_start(iy) <= g
    int iy = (int)((sqrtf((float)(8 * g + 9)) - 3.0f) * 0.5f);
    while (row_start(iy + 1) <= g) ++iy;
    while (row_start(iy) > g) --iy;

    // ---- prime: full prefetch of the first tile (12 loads) ----
    bf16x8 pA0h, pA0m, pA0l, pA1h, pA1m, pA1l;   // head A, halves 0/1
    bf16x8 pB0h, pB0m, pB0l, pB1h, pB1m, pB1l;   // head B, halves 0/1
    {
        const u32 j0 = (u32)((g - row_start(iy)) * 16) * DH;
        pA0h = *(const bf16x8*)(k_hi + kbA + j0);
        pA0m = *(const bf16x8*)(k_mi + kbA + j0);
        pA0l = *(const bf16x8*)(k_lo + kbA + j0);
        pA1h = *(const bf16x8*)(k_hi + kbA + j0 + 32u);
        pA1m = *(const bf16x8*)(k_mi + kbA + j0 + 32u);
        pA1l = *(const bf16x8*)(k_lo + kbA + j0 + 32u);
        pB0h = *(const bf16x8*)(k_hi + kbB + j0);
        pB0m = *(const bf16x8*)(k_mi + kbB + j0);
        pB0l = *(const bf16x8*)(k_lo + kbB + j0);
        pB1h = *(const bf16x8*)(k_hi + kbB + j0 + 32u);
        pB1m = *(const bf16x8*)(k_mi + kbB + j0 + 32u);
        pB1l = *(const bf16x8*)(k_lo + kbB + j0 + 32u);
    }

    while (g < gend) {
        const int ntiles = iy + 2;
        const int Srow0  = row_start(iy);
        int jt = g - Srow0;
        const int nrow   = min(ntiles - jt, gend - g);
        const int jt_hi  = jt + nrow;
        const int i0     = iy * 16;
        const int slot   = kb - blk_of(Srow0);

        // ---- Q A-frags for (b, iy): 2 heads/wave x 2 halves x 3 splits ----
        bf16x8 qh[2][2], qm[2][2], ql[2][2];
        {
            const float* qrow = q_all + (size_t)(b * NN + i0 + ln16) * DIM;
            #pragma unroll
            for (int h2 = 0; h2 < 2; ++h2) {
                const int h = wave * 2 + h2;
                #pragma unroll
                for (int half = 0; half < 2; ++half) {
                    const float* src = qrow + h * 64 + half * 32 + quad * 8;
                    float4 u0 = *(const float4*)src;
                    float4 u1 = *(const float4*)(src + 4);
                    float xv[8] = {u0.x, u0.y, u0.z, u0.w, u1.x, u1.y, u1.z, u1.w};
                    u16 eh[8], em[8], el[8];
                    #pragma unroll
                    for (int e = 0; e < 8; ++e) {
                        eh[e] = f2bf(xv[e]);
                        float d1 = xv[e] - bfval(eh[e]);
                        em[e] = f2bf(d1);
                        el[e] = f2bf(d1 - bfval(em[e]));
                    }
                    qh[h2][half] = *(bf16x8*)eh;
                    qm[h2][half] = *(bf16x8*)em;
                    ql[h2][half] = *(bf16x8*)el;
                }
            }
        }

        float tv[8];
        int   tx[8];
        #pragma unroll
        for (int t = 0; t < 8; ++t) { tv[t] = -1e30f; tx[t] = 0; }
        const int jlim = NM + i0 + ti_r;

        int par = 0;
        for (; jt < jt_hi; ++jt, par ^= 1) {
            float* Sb = S + par * 4096;

            {   // ---- head A (wave*2): all operands prefetched ----
                f32x4 acc = {};
                acc = MFMA16(qm[0][0], pA0m, acc);
                acc = MFMA16(qh[0][0], pA0l, acc);
                acc = MFMA16(ql[0][0], pA0h, acc);
                acc = MFMA16(qh[0][0], pA0m, acc);
                acc = MFMA16(qm[0][0], pA0h, acc);
                acc = MFMA16(qh[0][0], pA0h, acc);
                acc = MFMA16(qm[0][1], pA1m, acc);
                acc = MFMA16(qh[0][1], pA1l, acc);
                acc = MFMA16(ql[0][1], pA1h, acc);
                acc = MFMA16(qh[0][1], pA1m, acc);
                acc = MFMA16(qm[0][1], pA1h, acc);
                acc = MFMA16(qh[0][1], pA1h, acc);
                const int h = wave * 2;
                #pragma unroll
                for (int r = 0; r < 4; ++r) {
                    int i   = quad * 4 + r;
                    int rot = ((ln16 >> 2) + i + (i >> 2)) & 3;
                    Sb[h * 256 + i * 16 + rot * 4 + (ln16 & 3)] = acc[r];
                }
            }
            {   // ---- head B (wave*2+1) ----
                f32x4 acc = {};
                acc = MFMA16(qm[1][0], pB0m, acc);
                acc = MFMA16(qh[1][0], pB0l, acc);
                acc = MFMA16(ql[1][0], pB0h, acc);
                acc = MFMA16(qh[1][0], pB0m, acc);
                acc = MFMA16(qm[1][0], pB0h, acc);
                acc = MFMA16(qh[1][0], pB0h, acc);
                acc = MFMA16(qm[1][1], pB1m, acc);
                acc = MFMA16(qh[1][1], pB1l, acc);
                acc = MFMA16(ql[1][1], pB1h, acc);
                acc = MFMA16(qh[1][1], pB1m, acc);
                acc = MFMA16(qm[1][1], pB1h, acc);
                acc = MFMA16(qh[1][1], pB1h, acc);
                const int h = wave * 2 + 1;
                #pragma unroll
                for (int r = 0; r < 4; ++r) {
                    int i   = quad * 4 + r;
                    int rot = ((ln16 >> 2) + i + (i >> 2)) & 3;
                    Sb[h * 256 + i * 16 + rot * 4 + (ln16 & 3)] = acc[r];
                }
            }

            // ---- full prefetch of next tile (cross-row continuous):
            // K addr depends only on jt; next row starts at jt=0.
            {
                const int jt_next = (jt + 1 < jt_hi) ? jt + 1 : 0;
                const u32 jn = (u32)(jt_next * 16) * DH;
                pA0h = *(const bf16x8*)(k_hi + kbA + jn);
                pA0m = *(const bf16x8*)(k_mi + kbA + jn);
                pA0l = *(const bf16x8*)(k_lo + kbA + jn);
                pA1h = *(const bf16x8*)(k_hi + kbA + jn + 32u);
                pA1m = *(const bf16x8*)(k_mi + kbA + jn + 32u);
                pA1l = *(const bf16x8*)(k_lo + kbA + jn + 32u);
                pB0h = *(const bf16x8*)(k_hi + kbB + jn);
                pB0m = *(const bf16x8*)(k_mi + kbB + jn);
                pB0l = *(const bf16x8*)(k_lo + kbB + jn);
                pB1h = *(const bf16x8*)(k_hi + kbB + jn + 32u);
                pB1m = *(const bf16x8*)(k_mi + kbB + jn + 32u);
                pB1l = *(const bf16x8*)(k_lo + kbB + jn + 32u);
            }

            // ---- LDS handoff WITHOUT vmcnt drain ----
            asm volatile("s_waitcnt lgkmcnt(0)" ::: "memory");
            __builtin_amdgcn_s_barrier();
            __builtin_amdgcn_sched_barrier(0);   // pin: no mix-read hoisting

            // fused mix+scan for row (kk_r, ti_r), tj chunks {2*tjh, 2*tjh+1}
            const int jb = jt * 16;
            #pragma unroll
            for (int tc = 0; tc < 2; ++tc) {
                const int tjc = tjh * 2 + tc;
                const int rot = (tjc + ti_r + (ti_r >> 2)) & 3;
                const float* sp = Sb + ti_r * 16 + rot * 4;
                f32x4 m = {};
                #pragma unroll
                for (int h = 0; h < 16; ++h) {
                    float w  = pp[h * 16 + kk_r];             // broadcast b32
                    f32x4 s4 = *(const f32x4*)(sp + h * 256); // 4-way bcast b128
                    m += s4 * w;                              // v_pk_fma_f32 x2
                }
                const int jb2 = jb + tjc * 4;
                #pragma unroll
                for (int e = 0; e < 4; ++e) {
                    float c = m[e];
                    int j = jb2 + e;
                    if (j <= jlim && c > tv[7]) {
                        #pragma unroll
                        for (int t = 7; t >= 1; --t) {
                            if (c > tv[t - 1])      { tv[t] = tv[t - 1]; tx[t] = tx[t - 1]; }
                            else if (c > tv[t])     { tv[t] = c;         tx[t] = j; }
                        }
                        if (c > tv[0]) { tv[0] = c; tx[0] = j; }
                    }
                }
            }
            // no trailing barrier: next tile writes the other S buffer; the
            // per-tile barrier above orders reads(t) before writes(t+2).
        }

        // ---- row flush: merge tj-halves, write ws slot ----
        __syncthreads();                         // all scans for this row done
        if (tjh == 1) {
            #pragma unroll
            for (int t = 0; t < 8; ++t) {
                scr[srow * 8 + t]        = tv[t];
                scr[2048 + srow * 8 + t] = __int_as_float(tx[t]);
            }
        }
        __syncthreads();
        if (tjh == 0) {
            #pragma unroll
            for (int t2 = 0; t2 < 8; ++t2) {
                float c = scr[srow * 8 + t2];
                int   j = __float_as_int(scr[2048 + srow * 8 + t2]);
                if (c > tv[7]) {
                    #pragma unroll
                    for (int t = 7; t >= 1; --t) {
                        if (c > tv[t - 1])      { tv[t] = tv[t - 1]; tx[t] = tx[t - 1]; }
                        else if (c > tv[t])     { tv[t] = c;         tx[t] = j; }
                    }
                    if (c > tv[0]) { tv[0] = c; tx[0] = j; }
                }
            }
            size_t base = ((((size_t)b * HS + kk_r) * NN + i0 + ti_r) * JC + slot) * 8;
            #pragma unroll
            for (int t = 0; t < 8; ++t) {
                ws_val[base + t] = tv[t];
                ws_idx[base + t] = (u16)tx[t];
            }
        }

        g += nrow;
        ++iy;                                    // valid when row exhausted;
    }                                            // otherwise g==gend -> exit
}

// ---------------------------------------------------------------------------
// Phase 2: merge partial top-8s -> softmax -> sparse PV (bf16 V ws, f32 mem_v)
// -> fused out-proj with pre-transposed bf16 WoT (vector B-frag loads).
// Slot count per row = number of tile-range blocks covering the row.
// ---------------------------------------------------------------------------
__global__ __launch_bounds__(256) void merge_pv_kernel(
    const u16* __restrict__ v_bf, const float* __restrict__ mem_v,
    const float* __restrict__ ws_val, const u16* __restrict__ ws_idx,
    const float* __restrict__ post, const u16* __restrict__ wot,
    const float* __restrict__ bo, float* __restrict__ out)
{
    __shared__ __align__(16) float fsm[13312];
    float* dotsm = fsm + 8704;     // [4096]: w park [0..2047], j park [2048..4095]
    float* pp2   = fsm + 13056;    // [256] post_proj
    u16*   arows = (u16*)fsm;      // [16][1032] bf16 (PV rows)

    const int tid = threadIdx.x;
    const int b   = blockIdx.y;
    const int i0  = blockIdx.x * 16;
    const int ntiles = blockIdx.x + 2;
    const int Srow0  = row_start(blockIdx.x);
    const int jc_cnt = blk_of(Srow0 + ntiles - 1) - blk_of(Srow0) + 1;

    pp2[tid] = post[tid];

    const int kk_r = tid & 15, ti_r = tid >> 4;

    float tv[8];
    int   tx[8];
    #pragma unroll
    for (int t = 0; t < 8; ++t) { tv[t] = -1e30f; tx[t] = 0; }

    size_t rbase = (((size_t)b * HS + kk_r) * NN + i0 + ti_r) * JC;
    for (int jc = 0; jc < jc_cnt; ++jc) {
        #pragma unroll
        for (int t2 = 0; t2 < 8; ++t2) {
            float c = ws_val[(rbase + jc) * 8 + t2];
            int   j = ws_idx[(rbase + jc) * 8 + t2];
            if (c > tv[7]) {
                #pragma unroll
                for (int t = 7; t >= 1; --t) {
                    if (c > tv[t - 1])      { tv[t] = tv[t - 1]; tx[t] = tx[t - 1]; }
                    else if (c > tv[t])     { tv[t] = c;         tx[t] = j; }
                }
                if (c > tv[0]) { tv[0] = c; tx[0] = j; }
            }
        }
    }

    float m = tv[0];
    float wv[8], wsum = 0.f;
    #pragma unroll
    for (int t = 0; t < 8; ++t) { wv[t] = __expf(tv[t] - m); wsum += wv[t]; }
    float inv = 1.f / wsum;

    #pragma unroll
    for (int t = 0; t < 8; ++t) {
        dotsm[(kk_r * 16 + ti_r) * 8 + t]        = wv[t] * inv;
        dotsm[2048 + (kk_r * 16 + ti_r) * 8 + t] = __int_as_float(tx[t]);
    }
    __syncthreads();

    // PV: thread = (ti_o, k2)
    const int ti_o = tid >> 4, k2 = tid & 15;
    {
        float acc[64];
        #pragma unroll
        for (int d = 0; d < 64; ++d) acc[d] = 0.f;
        const u16*   vws_base  = v_bf  + (size_t)(b * HS + k2) * NN * DH;
        const float* vmem_base = mem_v + (size_t)k2 * NM * DH;

        for (int kk = 0; kk < 16; ++kk) {
            float p2 = pp2[kk * 16 + k2];
            for (int t = 0; t < 8; ++t) {
                float w = dotsm[(kk * 16 + ti_o) * 8 + t] * p2;
                int j = __float_as_int(dotsm[2048 + (kk * 16 + ti_o) * 8 + t]);
                if (j < NM) {
                    const float* vr = vmem_base + (size_t)j * DH;
                    #pragma unroll
                    for (int r = 0; r < 16; ++r) {
                        float4 u = *(const float4*)&vr[r * 4];
                        acc[r * 4 + 0] += w * u.x; acc[r * 4 + 1] += w * u.y;
                        acc[r * 4 + 2] += w * u.z; acc[r * 4 + 3] += w * u.w;
                    }
                } else {
                    const uint4* vr = (const uint4*)(vws_base + (size_t)(j - NM) * DH);
                    #pragma unroll
                    for (int r = 0; r < 8; ++r) {
                        uint4 u = vr[r];
                        acc[r * 8 + 0] += w * lo16(u.x); acc[r * 8 + 1] += w * hi16(u.x);
                        acc[r * 8 + 2] += w * lo16(u.y); acc[r * 8 + 3] += w * hi16(u.y);
                        acc[r * 8 + 4] += w * lo16(u.z); acc[r * 8 + 5] += w * hi16(u.z);
                        acc[r * 8 + 6] += w * lo16(u.w); acc[r * 8 + 7] += w * hi16(u.w);
                    }
                }
            }
        }
        #pragma unroll
        for (int d = 0; d < 64; ++d) {
            float o = acc[d];
            o = (o == o) ? o : 1e4f;             // V-side NaN sentinel (diagnostic)
            arows[ti_o * 1032 + k2 * 64 + d] = f2bf(o);
        }
    }
    __syncthreads();

    // fused out-projection: out_rows(16x1024) = arows(16x1024) @ Wo + bo
    const int wave = tid >> 6, lane = tid & 63;
    const int ln16 = lane & 15, quad = lane >> 4;

    f32x4 oacc[16];
    #pragma unroll
    for (int t = 0; t < 16; ++t) {
        float bv = bo[(t * 4 + wave) * 16 + ln16];
        oacc[t][0] = bv; oacc[t][1] = bv; oacc[t][2] = bv; oacc[t][3] = bv;
    }

    for (int k0 = 0; k0 < 1024; k0 += 32) {
        bf16x8 af = *(const bf16x8*)&arows[ln16 * 1032 + k0 + quad * 8];
        #pragma unroll
        for (int t = 0; t < 16; ++t) {
            const int n = (t * 4 + wave) * 16 + ln16;
            bf16x8 bf_ = *(const bf16x8*)&wot[(size_t)n * 1024 + k0 + quad * 8];
            oacc[t] = MFMA16(af, bf_, oacc[t]);
        }
    }

    #pragma unroll
    for (int t = 0; t < 16; ++t) {
        const int n = (t * 4 + wave) * 16 + ln16;
        #pragma unroll
        for (int r = 0; r < 4; ++r) {
            int row = quad * 4 + r;
            out[(size_t)(b * NN + i0 + row) * DIM + n] = oacc[t][r];
        }
    }
}

// ---------------------------------------------------------------------------
extern "C" void kernel_launch(void* const* d_in, const int* in_sizes, int n_in,
                              void* d_out, int out_size, void* d_ws, size_t ws_size,
                              hipStream_t stream)
{
    (void)in_sizes; (void)n_in; (void)out_size; (void)ws_size;
    const float* x     = (const float*)d_in[0];
    const float* Wq    = (const float*)d_in[1];
    const float* Wk    = (const float*)d_in[2];
    const float* Wv    = (const float*)d_in[3];
    const float* pre   = (const float*)d_in[4];
    const float* post  = (const float*)d_in[5];
    const float* mem_k = (const float*)d_in[6];
    const float* mem_v = (const float*)d_in[7];
    const float* Wo    = (const float*)d_in[8];
    const float* bo    = (const float*)d_in[9];

    // workspace (51.6 MB total, < 54.6 proven):
    //   K splits 3x bf16 [2][16][2064][64]            = 25.36 MB
    //   V bf16 [2][16][2048][64]                      =  8.39 MB
    //   partial top-8 val f32 [2][16][2048][JC=5][8]  = 10.49 MB
    //   partial top-8 idx u16                          =  5.24 MB
    //   WoT bf16 [1024][1024]                         =  2.10 MB
    u16*   k_sp   = (u16*)d_ws;
    u16*   v_bf   = k_sp + 3 * SPLITSZ;
    float* ws_val = (float*)(v_bf + (size_t)BB * HS * NN * DH);
    u16*   ws_idx = (u16*)(ws_val + (size_t)BB * HS * NN * JC * 8);
    u16*   wot    = ws_idx + (size_t)BB * HS * NN * JC * 8;
    float* q_tmp  = (float*)d_out;                           // Q f32 [b*n][1024]

    prep_mem_kernel<<<128, 256, 0, stream>>>(mem_k, k_sp);
    prep_wot_kernel<<<4096, 256, 0, stream>>>(Wo, wot);

    dim3 gg(32, 16);
    gemm_kernel<<<gg, 256, 0, stream>>>(x, Wq, nullptr, q_tmp, 1);  // Q -> d_out
    gemm_kernel<<<gg, 256, 0, stream>>>(x, Wk, k_sp, nullptr, 2);   // K -> split planes
    gemm_kernel<<<gg, 256, 0, stream>>>(x, Wv, v_bf, nullptr, 0);   // V -> bf16 ws (4-pass)

    // uniform tile-partition grid: 512 blocks = exactly 2 resident per CU
    score_topk_kernel<<<512, 512, 0, stream>>>(k_sp, k_sp + SPLITSZ,
                                               k_sp + 2 * SPLITSZ,
                                               (const float*)d_out,
                                               pre, ws_val, ws_idx);

    dim3 ga(128, 2);
    merge_pv_kernel<<<ga, 256, 0, stream>>>(v_bf, mem_v, ws_val, ws_idx,
                                            post, wot, bo, (float*)d_out);
}

// Round 11
// 986.642 us; speedup vs baseline: 1.2437x; 1.2437x over previous
//
#include <hip/hip_runtime.h>
#include <hip/hip_bf16.h>

typedef unsigned short u16;
typedef unsigned int   u32;

#define BB   2
#define NN   2048
#define HS   16
#define DH   64
#define NM   16
#define JT   2064   // NM + NN
#define DIM  1024
#define JC   5      // partial top-8 slots per row (max blocks covering a row)
#define NBB  256    // blocks per batch (b)
#define TOTT 8384   // total j-tiles per batch: sum_{iy}(iy+2)

#define SPLITSZ ((size_t)BB * HS * JT * DH)   // elements per K-split plane

__device__ __forceinline__ float bfval(u16 u) { return __uint_as_float(((u32)u) << 16); }
__device__ __forceinline__ float lo16(u32 u)  { return __uint_as_float(u << 16); }
__device__ __forceinline__ float hi16(u32 u)  { return __uint_as_float(u & 0xffff0000u); }
__device__ __forceinline__ u16 f2bf(float f)
{
    __hip_bfloat16 h = __float2bfloat16(f);
    return *(u16*)&h;
}

// tile-space partition: block k (k=0..255 per b) owns tiles [start(k), start(k+1))
// start(k) = floor(131k/4)  (TOTT/NBB = 32.75 = 131/4, exact)
__device__ __forceinline__ int blk_start(int k) { return (131 * k) >> 2; }
__device__ __forceinline__ int blk_of(int g)
{
    int k = (4 * g) / 131;
    while (blk_start(k + 1) <= g) ++k;
    while (blk_start(k) > g) --k;
    return k;
}
// row (iy) starts at tile S(iy) = iy*(iy+3)/2
__device__ __forceinline__ int row_start(int iy) { return (iy * (iy + 3)) >> 1; }

typedef __bf16 bf16x8 __attribute__((ext_vector_type(8)));
typedef float  f32x4  __attribute__((ext_vector_type(4)));

#define MFMA16(A, B, C) __builtin_amdgcn_mfma_f32_16x16x32_bf16(A, B, C, 0, 0, 0)

// ---------------------------------------------------------------------------
// mem_k rows -> K-split planes (hi/mid/lo bf16) at key rows 0..15.
// ---------------------------------------------------------------------------
__global__ void prep_mem_kernel(const float* __restrict__ mem_k, u16* __restrict__ k_sp)
{
    int t = blockIdx.x * 256 + threadIdx.x;          // 0 .. 32767
    int d = t & 63, j = (t >> 6) & 15, h = (t >> 10) & 15, b = (t >> 14) & 1;
    float x = mem_k[(h * NM + j) * DH + d];
    size_t di = ((size_t)(b * HS + h) * JT + j) * DH + d;
    u16 sh = f2bf(x);
    float d1 = x - bfval(sh);
    u16 sm = f2bf(d1);
    u16 sl = f2bf(d1 - bfval(sm));
    k_sp[di] = sh; k_sp[di + SPLITSZ] = sm; k_sp[di + 2 * SPLITSZ] = sl;
}

// ---------------------------------------------------------------------------
// Wo f32 [k][n] -> WoT bf16 [n][k] (B-frag native layout for the epilogue).
// ---------------------------------------------------------------------------
__global__ void prep_wot_kernel(const float* __restrict__ Wo, u16* __restrict__ wot)
{
    int t = blockIdx.x * 256 + threadIdx.x;          // 0 .. 1048575
    int k = t & 1023, n = t >> 10;
    wot[(size_t)n * 1024 + k] = f2bf(Wo[(size_t)k * 1024 + n]);
}

// ---------------------------------------------------------------------------
// Exact-f32 GEMM via bf16 split MFMA (core verified R7-R9).
// mode 0: V -> bf16 scatter. 4-pass (mm,hm,mh,hh) — dropped hl/lh terms
//         are O(2^-16) relative, two orders below V's own bf16 rounding.
// mode 1: Q -> f32 row-major (6-pass exact: feeds score top-k, keep).
// mode 2: K -> hi/mid/lo split planes (6-pass exact).
// ---------------------------------------------------------------------------
__global__ __launch_bounds__(256) void gemm_kernel(
    const float* __restrict__ A, const float* __restrict__ Bw,
    u16* __restrict__ dst16, float* __restrict__ dstf, int mode)
{
    __shared__ __align__(16) u16 a_h[128][32];
    __shared__ __align__(16) u16 a_m[128][32];
    __shared__ __align__(16) u16 a_l[128][32];
    __shared__ __align__(16) u16 b_hT[64][32];
    __shared__ __align__(16) u16 b_mT[64][32];
    __shared__ __align__(16) u16 b_lT[64][32];

    const int tid  = threadIdx.x;
    const int m0   = blockIdx.x * 128;
    const int n0   = blockIdx.y * 64;
    const int wave = tid >> 6, lane = tid & 63;
    const int ln16 = lane & 15, quad = lane >> 4;

    const int arow = tid >> 1;            // 0..127
    const int ac   = (tid & 1) * 16;      // 0 or 16
    const int brow = tid >> 3;            // 0..31
    const int bc   = (tid & 7) * 8;       // 0..56

    f32x4 acc[8] = {};

    for (int k0 = 0; k0 < 1024; k0 += 32) {
        float av[16];
        {
            const float4* ap = (const float4*)&A[(size_t)(m0 + arow) * 1024 + k0 + ac];
            *(float4*)&av[0]  = ap[0]; *(float4*)&av[4]  = ap[1];
            *(float4*)&av[8]  = ap[2]; *(float4*)&av[12] = ap[3];
        }
        float bv[8];
        {
            const float4* bp = (const float4*)&Bw[(size_t)(k0 + brow) * 1024 + n0 + bc];
            *(float4*)&bv[0] = bp[0]; *(float4*)&bv[4] = bp[1];
        }
        u16 ah[16], am[16], al[16], bh[8], bm[8], bl[8];
        #pragma unroll
        for (int e = 0; e < 16; ++e) {
            ah[e] = f2bf(av[e]);
            float d1 = av[e] - bfval(ah[e]);
            am[e] = f2bf(d1);
            al[e] = (mode != 0) ? f2bf(d1 - bfval(am[e])) : (u16)0;
        }
        #pragma unroll
        for (int e = 0; e < 8; ++e) {
            bh[e] = f2bf(bv[e]);
            float d1 = bv[e] - bfval(bh[e]);
            bm[e] = f2bf(d1);
            bl[e] = (mode != 0) ? f2bf(d1 - bfval(bm[e])) : (u16)0;
        }
        __syncthreads();
        *(uint4*)&a_h[arow][ac]     = ((uint4*)ah)[0];
        *(uint4*)&a_h[arow][ac + 8] = ((uint4*)ah)[1];
        *(uint4*)&a_m[arow][ac]     = ((uint4*)am)[0];
        *(uint4*)&a_m[arow][ac + 8] = ((uint4*)am)[1];
        if (mode != 0) {
            *(uint4*)&a_l[arow][ac]     = ((uint4*)al)[0];
            *(uint4*)&a_l[arow][ac + 8] = ((uint4*)al)[1];
        }
        #pragma unroll
        for (int e = 0; e < 8; ++e) {
            b_hT[bc + e][brow] = bh[e];
            b_mT[bc + e][brow] = bm[e];
            if (mode != 0) b_lT[bc + e][brow] = bl[e];
        }
        __syncthreads();

        bf16x8 a0h = *(const bf16x8*)&a_h[wave * 32 + ln16][quad * 8];
        bf16x8 a0m = *(const bf16x8*)&a_m[wave * 32 + ln16][quad * 8];
        bf16x8 a1h = *(const bf16x8*)&a_h[wave * 32 + 16 + ln16][quad * 8];
        bf16x8 a1m = *(const bf16x8*)&a_m[wave * 32 + 16 + ln16][quad * 8];
        bf16x8 a0l = {}, a1l = {};
        if (mode != 0) {
            a0l = *(const bf16x8*)&a_l[wave * 32 + ln16][quad * 8];
            a1l = *(const bf16x8*)&a_l[wave * 32 + 16 + ln16][quad * 8];
        }
        #pragma unroll
        for (int c = 0; c < 4; ++c) {
            bf16x8 bh_ = *(const bf16x8*)&b_hT[c * 16 + ln16][quad * 8];
            bf16x8 bm_ = *(const bf16x8*)&b_mT[c * 16 + ln16][quad * 8];
            acc[c]     = MFMA16(a0m, bm_, acc[c]);
            acc[c]     = MFMA16(a0h, bm_, acc[c]);
            acc[c]     = MFMA16(a0m, bh_, acc[c]);
            acc[c]     = MFMA16(a0h, bh_, acc[c]);
            acc[4 + c] = MFMA16(a1m, bm_, acc[4 + c]);
            acc[4 + c] = MFMA16(a1h, bm_, acc[4 + c]);
            acc[4 + c] = MFMA16(a1m, bh_, acc[4 + c]);
            acc[4 + c] = MFMA16(a1h, bh_, acc[4 + c]);
            if (mode != 0) {
                bf16x8 bl_ = *(const bf16x8*)&b_lT[c * 16 + ln16][quad * 8];
                acc[c]     = MFMA16(a0h, bl_, acc[c]);
                acc[c]     = MFMA16(a0l, bh_, acc[c]);
                acc[4 + c] = MFMA16(a1h, bl_, acc[4 + c]);
                acc[4 + c] = MFMA16(a1l, bh_, acc[4 + c]);
            }
        }
    }

    #pragma unroll
    for (int hf = 0; hf < 2; ++hf) {
        #pragma unroll
        for (int c = 0; c < 4; ++c) {
            #pragma unroll
            for (int r = 0; r < 4; ++r) {
                int row = m0 + wave * 32 + hf * 16 + quad * 4 + r;
                int col = n0 + c * 16 + ln16;
                float v = acc[hf * 4 + c][r];
                if (mode == 1) {
                    dstf[(size_t)row * 1024 + col] = v;
                } else {
                    int b = row >> 11, i = row & 2047;
                    int hd = col >> 6, d = col & 63;
                    if (mode == 0) {
                        dst16[(((size_t)(b * HS + hd)) * NN + i) * DH + d] = f2bf(v);
                    } else {
                        size_t di = (((size_t)(b * HS + hd)) * JT + NM + i) * DH + d;
                        u16 sh = f2bf(v);
                        float d1 = v - bfval(sh);
                        u16 sm = f2bf(d1);
                        u16 sl = f2bf(d1 - bfval(sm));
                        dst16[di] = sh;
                        dst16[di + SPLITSZ] = sm;
                        dst16[di + 2 * SPLITSZ] = sl;
                    }
                }
            }
        }
    }
}

// ---------------------------------------------------------------------------
// Phase 1 (MFMA): scores + partial top-8.
// R20 == R18 structure with PLAIN __launch_bounds__(512) — no second arg.
// Rule (R12 + R19, both measured): any second launch_bounds arg makes this
// allocator target 64 VGPR and spill (WRITE_SIZE 12->363 MB, dur +50%).
// Natural pressure: R17 measured 88 with half-prefetch; full prefetch adds
// ~24 VGPR -> est ~112, inside the 65-128 bracket without any cap.
//  - all 12 K loads for the NEXT tile issued after this tile's MFMAs,
//    in flight across the raw barrier (no vmcnt drain) + mix.
//  - jt_next = (jt+1<jt_hi) ? jt+1 : 0 pipelines across row boundaries.
// ---------------------------------------------------------------------------
__global__ __launch_bounds__(512) void score_topk_kernel(
    const u16* __restrict__ k_hi, const u16* __restrict__ k_mi,
    const u16* __restrict__ k_lo,
    const float* __restrict__ q_all, const float* __restrict__ pre,
    float* __restrict__ ws_val, u16* __restrict__ ws_idx)
{
    const int bid = blockIdx.x;                  // 0..511
    const int b   = bid >> 8;
    const int kb  = bid & 255;                   // striped: XCD = kb % 8

    int g = blk_start(kb);
    const int gend = blk_start(kb + 1);

    __shared__ __align__(16) float fsm[12544];
    float* S   = fsm;            // [2][16][256] dbuf, chunk-rotation swizzled
    float* pp  = fsm + 8192;     // [256] pre_proj * 0.125
    float* scr = fsm + 8448;     // [4096] row-flush merge scratch

    const int tid  = threadIdx.x;
    const int wave = tid >> 6, lane = tid & 63;
    const int ln16 = lane & 15, quad = lane >> 4;

    if (tid < 256) pp[tid] = pre[tid] * 0.125f;
    __syncthreads();                             // pp staged

    // scan-row ownership: waves 0-3 scan tj-half 0, waves 4-7 tj-half 1
    const int kk_r = (wave & 3) * 4 + (lane & 3);
    const int ti_r = lane >> 2;
    const int tjh  = wave >> 2;
    const int srow = kk_r * 16 + ti_r;           // scratch row id

    // u32 element offset base for this thread's K-row slice (b, lane row)
    const u32 kbase0 = ((u32)(b * HS) * JT + (u32)ln16) * DH + (u32)(quad * 8);
    const u32 hstep  = (u32)(JT * DH);           // head stride in elements
    const u32 kbA    = kbase0 + (u32)(wave * 2) * hstep;       // head wave*2
    const u32 kbB    = kbA + hstep;                            // head wave*2+1

    // initial row: largest iy with row_start(iy) <= g
    int iy = (int)((sqrtf((float)(8 * g + 9)) - 3.0f) * 0.5f);
    while (row_start(iy + 1) <= g) ++iy;
    while (row_start(iy) > g) --iy;

    // ---- prime: full prefetch of the first tile (12 loads) ----
    bf16x8 pA0h, pA0m, pA0l, pA1h, pA1m, pA1l;   // head A, halves 0/1
    bf16x8 pB0h, pB0m, pB0l, pB1h, pB1m, pB1l;   // head B, halves 0/1
    {
        const u32 j0 = (u32)((g - row_start(iy)) * 16) * DH;
        pA0h = *(const bf16x8*)(k_hi + kbA + j0);
        pA0m = *(const bf16x8*)(k_mi + kbA + j0);
        pA0l = *(const bf16x8*)(k_lo + kbA + j0);
        pA1h = *(const bf16x8*)(k_hi + kbA + j0 + 32u);
        pA1m = *(const bf16x8*)(k_mi + kbA + j0 + 32u);
        pA1l = *(const bf16x8*)(k_lo + kbA + j0 + 32u);
        pB0h = *(const bf16x8*)(k_hi + kbB + j0);
        pB0m = *(const bf16x8*)(k_mi + kbB + j0);
        pB0l = *(const bf16x8*)(k_lo + kbB + j0);
        pB1h = *(const bf16x8*)(k_hi + kbB + j0 + 32u);
        pB1m = *(const bf16x8*)(k_mi + kbB + j0 + 32u);
        pB1l = *(const bf16x8*)(k_lo + kbB + j0 + 32u);
    }

    while (g < gend) {
        const int ntiles = iy + 2;
        const int Srow0  = row_start(iy);
        int jt = g - Srow0;
        const int nrow   = min(ntiles - jt, gend - g);
        const int jt_hi  = jt + nrow;
        const int i0     = iy * 16;
        const int slot   = kb - blk_of(Srow0);

        // ---- Q A-frags for (b, iy): 2 heads/wave x 2 halves x 3 splits ----
        bf16x8 qh[2][2], qm[2][2], ql[2][2];
        {
            const float* qrow = q_all + (size_t)(b * NN + i0 + ln16) * DIM;
            #pragma unroll
            for (int h2 = 0; h2 < 2; ++h2) {
                const int h = wave * 2 + h2;
                #pragma unroll
                for (int half = 0; half < 2; ++half) {
                    const float* src = qrow + h * 64 + half * 32 + quad * 8;
                    float4 u0 = *(const float4*)src;
                    float4 u1 = *(const float4*)(src + 4);
                    float xv[8] = {u0.x, u0.y, u0.z, u0.w, u1.x, u1.y, u1.z, u1.w};
                    u16 eh[8], em[8], el[8];
                    #pragma unroll
                    for (int e = 0; e < 8; ++e) {
                        eh[e] = f2bf(xv[e]);
                        float d1 = xv[e] - bfval(eh[e]);
                        em[e] = f2bf(d1);
                        el[e] = f2bf(d1 - bfval(em[e]));
                    }
                    qh[h2][half] = *(bf16x8*)eh;
                    qm[h2][half] = *(bf16x8*)em;
                    ql[h2][half] = *(bf16x8*)el;
                }
            }
        }

        float tv[8];
        int   tx[8];
        #pragma unroll
        for (int t = 0; t < 8; ++t) { tv[t] = -1e30f; tx[t] = 0; }
        const int jlim = NM + i0 + ti_r;

        int par = 0;
        for (; jt < jt_hi; ++jt, par ^= 1) {
            float* Sb = S + par * 4096;

            {   // ---- head A (wave*2): all operands prefetched ----
                f32x4 acc = {};
                acc = MFMA16(qm[0][0], pA0m, acc);
                acc = MFMA16(qh[0][0], pA0l, acc);
                acc = MFMA16(ql[0][0], pA0h, acc);
                acc = MFMA16(qh[0][0], pA0m, acc);
                acc = MFMA16(qm[0][0], pA0h, acc);
                acc = MFMA16(qh[0][0], pA0h, acc);
                acc = MFMA16(qm[0][1], pA1m, acc);
                acc = MFMA16(qh[0][1], pA1l, acc);
                acc = MFMA16(ql[0][1], pA1h, acc);
                acc = MFMA16(qh[0][1], pA1m, acc);
                acc = MFMA16(qm[0][1], pA1h, acc);
                acc = MFMA16(qh[0][1], pA1h, acc);
                const int h = wave * 2;
                #pragma unroll
                for (int r = 0; r < 4; ++r) {
                    int i   = quad * 4 + r;
                    int rot = ((ln16 >> 2) + i + (i >> 2)) & 3;
                    Sb[h * 256 + i * 16 + rot * 4 + (ln16 & 3)] = acc[r];
                }
            }
            {   // ---- head B (wave*2+1) ----
                f32x4 acc = {};
                acc = MFMA16(qm[1][0], pB0m, acc);
                acc = MFMA16(qh[1][0], pB0l, acc);
                acc = MFMA16(ql[1][0], pB0h, acc);
                acc = MFMA16(qh[1][0], pB0m, acc);
                acc = MFMA16(qm[1][0], pB0h, acc);
                acc = MFMA16(qh[1][0], pB0h, acc);
                acc = MFMA16(qm[1][1], pB1m, acc);
                acc = MFMA16(qh[1][1], pB1l, acc);
                acc = MFMA16(ql[1][1], pB1h, acc);
                acc = MFMA16(qh[1][1], pB1m, acc);
                acc = MFMA16(qm[1][1], pB1h, acc);
                acc = MFMA16(qh[1][1], pB1h, acc);
                const int h = wave * 2 + 1;
                #pragma unroll
                for (int r = 0; r < 4; ++r) {
                    int i   = quad * 4 + r;
                    int rot = ((ln16 >> 2) + i + (i >> 2)) & 3;
                    Sb[h * 256 + i * 16 + rot * 4 + (ln16 & 3)] = acc[r];
                }
            }

            // ---- full prefetch of next tile (cross-row continuous):
            // K addr depends only on jt; next row starts at jt=0.
            {
                const int jt_next = (jt + 1 < jt_hi) ? jt + 1 : 0;
                const u32 jn = (u32)(jt_next * 16) * DH;
                pA0h = *(const bf16x8*)(k_hi + kbA + jn);
                pA0m = *(const bf16x8*)(k_mi + kbA + jn);
                pA0l = *(const bf16x8*)(k_lo + kbA + jn);
                pA1h = *(const bf16x8*)(k_hi + kbA + jn + 32u);
                pA1m = *(const bf16x8*)(k_mi + kbA + jn + 32u);
                pA1l = *(const bf16x8*)(k_lo + kbA + jn + 32u);
                pB0h = *(const bf16x8*)(k_hi + kbB + jn);
                pB0m = *(const bf16x8*)(k_mi + kbB + jn);
                pB0l = *(const bf16x8*)(k_lo + kbB + jn);
                pB1h = *(const bf16x8*)(k_hi + kbB + jn + 32u);
                pB1m = *(const bf16x8*)(k_mi + kbB + jn + 32u);
                pB1l = *(const bf16x8*)(k_lo + kbB + jn + 32u);
            }

            // ---- LDS handoff WITHOUT vmcnt drain ----
            asm volatile("s_waitcnt lgkmcnt(0)" ::: "memory");
            __builtin_amdgcn_s_barrier();
            __builtin_amdgcn_sched_barrier(0);   // pin: no mix-read hoisting

            // fused mix+scan for row (kk_r, ti_r), tj chunks {2*tjh, 2*tjh+1}
            const int jb = jt * 16;
            #pragma unroll
            for (int tc = 0; tc < 2; ++tc) {
                const int tjc = tjh * 2 + tc;
                const int rot = (tjc + ti_r + (ti_r >> 2)) & 3;
                const float* sp = Sb + ti_r * 16 + rot * 4;
                f32x4 m = {};
                #pragma unroll
                for (int h = 0; h < 16; ++h) {
                    float w  = pp[h * 16 + kk_r];             // broadcast b32
                    f32x4 s4 = *(const f32x4*)(sp + h * 256); // 4-way bcast b128
                    m += s4 * w;                              // v_pk_fma_f32 x2
                }
                const int jb2 = jb + tjc * 4;
                #pragma unroll
                for (int e = 0; e < 4; ++e) {
                    float c = m[e];
                    int j = jb2 + e;
                    if (j <= jlim && c > tv[7]) {
                        #pragma unroll
                        for (int t = 7; t >= 1; --t) {
                            if (c > tv[t - 1])      { tv[t] = tv[t - 1]; tx[t] = tx[t - 1]; }
                            else if (c > tv[t])     { tv[t] = c;         tx[t] = j; }
                        }
                        if (c > tv[0]) { tv[0] = c; tx[0] = j; }
                    }
                }
            }
            // no trailing barrier: next tile writes the other S buffer; the
            // per-tile barrier above orders reads(t) before writes(t+2).
        }

        // ---- row flush: merge tj-halves, write ws slot ----
        __syncthreads();                         // all scans for this row done
        if (tjh == 1) {
            #pragma unroll
            for (int t = 0; t < 8; ++t) {
                scr[srow * 8 + t]        = tv[t];
                scr[2048 + srow * 8 + t] = __int_as_float(tx[t]);
            }
        }
        __syncthreads();
        if (tjh == 0) {
            #pragma unroll
            for (int t2 = 0; t2 < 8; ++t2) {
                float c = scr[srow * 8 + t2];
                int   j = __float_as_int(scr[2048 + srow * 8 + t2]);
                if (c > tv[7]) {
                    #pragma unroll
                    for (int t = 7; t >= 1; --t) {
                        if (c > tv[t - 1])      { tv[t] = tv[t - 1]; tx[t] = tx[t - 1]; }
                        else if (c > tv[t])     { tv[t] = c;         tx[t] = j; }
                    }
                    if (c > tv[0]) { tv[0] = c; tx[0] = j; }
                }
            }
            size_t base = ((((size_t)b * HS + kk_r) * NN + i0 + ti_r) * JC + slot) * 8;
            #pragma unroll
            for (int t = 0; t < 8; ++t) {
                ws_val[base + t] = tv[t];
                ws_idx[base + t] = (u16)tx[t];
            }
        }

        g += nrow;
        ++iy;                                    // valid when row exhausted;
    }                                            // otherwise g==gend -> exit
}

// ---------------------------------------------------------------------------
// Phase 2: merge partial top-8s -> softmax -> sparse PV (bf16 V ws, f32 mem_v)
// -> fused out-proj with pre-transposed bf16 WoT (vector B-frag loads).
// Slot count per row = number of tile-range blocks covering the row.
// ---------------------------------------------------------------------------
__global__ __launch_bounds__(256) void merge_pv_kernel(
    const u16* __restrict__ v_bf, const float* __restrict__ mem_v,
    const float* __restrict__ ws_val, const u16* __restrict__ ws_idx,
    const float* __restrict__ post, const u16* __restrict__ wot,
    const float* __restrict__ bo, float* __restrict__ out)
{
    __shared__ __align__(16) float fsm[13312];
    float* dotsm = fsm + 8704;     // [4096]: w park [0..2047], j park [2048..4095]
    float* pp2   = fsm + 13056;    // [256] post_proj
    u16*   arows = (u16*)fsm;      // [16][1032] bf16 (PV rows)

    const int tid = threadIdx.x;
    const int b   = blockIdx.y;
    const int i0  = blockIdx.x * 16;
    const int ntiles = blockIdx.x + 2;
    const int Srow0  = row_start(blockIdx.x);
    const int jc_cnt = blk_of(Srow0 + ntiles - 1) - blk_of(Srow0) + 1;

    pp2[tid] = post[tid];

    const int kk_r = tid & 15, ti_r = tid >> 4;

    float tv[8];
    int   tx[8];
    #pragma unroll
    for (int t = 0; t < 8; ++t) { tv[t] = -1e30f; tx[t] = 0; }

    size_t rbase = (((size_t)b * HS + kk_r) * NN + i0 + ti_r) * JC;
    for (int jc = 0; jc < jc_cnt; ++jc) {
        #pragma unroll
        for (int t2 = 0; t2 < 8; ++t2) {
            float c = ws_val[(rbase + jc) * 8 + t2];
            int   j = ws_idx[(rbase + jc) * 8 + t2];
            if (c > tv[7]) {
                #pragma unroll
                for (int t = 7; t >= 1; --t) {
                    if (c > tv[t - 1])      { tv[t] = tv[t - 1]; tx[t] = tx[t - 1]; }
                    else if (c > tv[t])     { tv[t] = c;         tx[t] = j; }
                }
                if (c > tv[0]) { tv[0] = c; tx[0] = j; }
            }
        }
    }

    float m = tv[0];
    float wv[8], wsum = 0.f;
    #pragma unroll
    for (int t = 0; t < 8; ++t) { wv[t] = __expf(tv[t] - m); wsum += wv[t]; }
    float inv = 1.f / wsum;

    #pragma unroll
    for (int t = 0; t < 8; ++t) {
        dotsm[(kk_r * 16 + ti_r) * 8 + t]        = wv[t] * inv;
        dotsm[2048 + (kk_r * 16 + ti_r) * 8 + t] = __int_as_float(tx[t]);
    }
    __syncthreads();

    // PV: thread = (ti_o, k2)
    const int ti_o = tid >> 4, k2 = tid & 15;
    {
        float acc[64];
        #pragma unroll
        for (int d = 0; d < 64; ++d) acc[d] = 0.f;
        const u16*   vws_base  = v_bf  + (size_t)(b * HS + k2) * NN * DH;
        const float* vmem_base = mem_v + (size_t)k2 * NM * DH;

        for (int kk = 0; kk < 16; ++kk) {
            float p2 = pp2[kk * 16 + k2];
            for (int t = 0; t < 8; ++t) {
                float w = dotsm[(kk * 16 + ti_o) * 8 + t] * p2;
                int j = __float_as_int(dotsm[2048 + (kk * 16 + ti_o) * 8 + t]);
                if (j < NM) {
                    const float* vr = vmem_base + (size_t)j * DH;
                    #pragma unroll
                    for (int r = 0; r < 16; ++r) {
                        float4 u = *(const float4*)&vr[r * 4];
                        acc[r * 4 + 0] += w * u.x; acc[r * 4 + 1] += w * u.y;
                        acc[r * 4 + 2] += w * u.z; acc[r * 4 + 3] += w * u.w;
                    }
                } else {
                    const uint4* vr = (const uint4*)(vws_base + (size_t)(j - NM) * DH);
                    #pragma unroll
                    for (int r = 0; r < 8; ++r) {
                        uint4 u = vr[r];
                        acc[r * 8 + 0] += w * lo16(u.x); acc[r * 8 + 1] += w * hi16(u.x);
                        acc[r * 8 + 2] += w * lo16(u.y); acc[r * 8 + 3] += w * hi16(u.y);
                        acc[r * 8 + 4] += w * lo16(u.z); acc[r * 8 + 5] += w * hi16(u.z);
                        acc[r * 8 + 6] += w * lo16(u.w); acc[r * 8 + 7] += w * hi16(u.w);
                    }
                }
            }
        }
        #pragma unroll
        for (int d = 0; d < 64; ++d) {
            float o = acc[d];
            o = (o == o) ? o : 1e4f;             // V-side NaN sentinel (diagnostic)
            arows[ti_o * 1032 + k2 * 64 + d] = f2bf(o);
        }
    }
    __syncthreads();

    // fused out-projection: out_rows(16x1024) = arows(16x1024) @ Wo + bo
    const int wave = tid >> 6, lane = tid & 63;
    const int ln16 = lane & 15, quad = lane >> 4;

    f32x4 oacc[16];
    #pragma unroll
    for (int t = 0; t < 16; ++t) {
        float bv = bo[(t * 4 + wave) * 16 + ln16];
        oacc[t][0] = bv; oacc[t][1] = bv; oacc[t][2] = bv; oacc[t][3] = bv;
    }

    for (int k0 = 0; k0 < 1024; k0 += 32) {
        bf16x8 af = *(const bf16x8*)&arows[ln16 * 1032 + k0 + quad * 8];
        #pragma unroll
        for (int t = 0; t < 16; ++t) {
            const int n = (t * 4 + wave) * 16 + ln16;
            bf16x8 bf_ = *(const bf16x8*)&wot[(size_t)n * 1024 + k0 + quad * 8];
            oacc[t] = MFMA16(af, bf_, oacc[t]);
        }
    }

    #pragma unroll
    for (int t = 0; t < 16; ++t) {
        const int n = (t * 4 + wave) * 16 + ln16;
        #pragma unroll
        for (int r = 0; r < 4; ++r) {
            int row = quad * 4 + r;
            out[(size_t)(b * NN + i0 + row) * DIM + n] = oacc[t][r];
        }
    }
}

// ---------------------------------------------------------------------------
extern "C" void kernel_launch(void* const* d_in, const int* in_sizes, int n_in,
                              void* d_out, int out_size, void* d_ws, size_t ws_size,
                              hipStream_t stream)
{
    (void)in_sizes; (void)n_in; (void)out_size; (void)ws_size;
    const float* x     = (const float*)d_in[0];
    const float* Wq    = (const float*)d_in[1];
    const float* Wk    = (const float*)d_in[2];
    const float* Wv    = (const float*)d_in[3];
    const float* pre   = (const float*)d_in[4];
    const float* post  = (const float*)d_in[5];
    const float* mem_k = (const float*)d_in[6];
    const float* mem_v = (const float*)d_in[7];
    const float* Wo    = (const float*)d_in[8];
    const float* bo    = (const float*)d_in[9];

    // workspace (51.6 MB total, < 54.6 proven):
    //   K splits 3x bf16 [2][16][2064][64]            = 25.36 MB
    //   V bf16 [2][16][2048][64]                      =  8.39 MB
    //   partial top-8 val f32 [2][16][2048][JC=5][8]  = 10.49 MB
    //   partial top-8 idx u16                          =  5.24 MB
    //   WoT bf16 [1024][1024]                         =  2.10 MB
    u16*   k_sp   = (u16*)d_ws;
    u16*   v_bf   = k_sp + 3 * SPLITSZ;
    float* ws_val = (float*)(v_bf + (size_t)BB * HS * NN * DH);
    u16*   ws_idx = (u16*)(ws_val + (size_t)BB * HS * NN * JC * 8);
    u16*   wot    = ws_idx + (size_t)BB * HS * NN * JC * 8;
    float* q_tmp  = (float*)d_out;                           // Q f32 [b*n][1024]

    prep_mem_kernel<<<128, 256, 0, stream>>>(mem_k, k_sp);
    prep_wot_kernel<<<4096, 256, 0, stream>>>(Wo, wot);

    dim3 gg(32, 16);
    gemm_kernel<<<gg, 256, 0, stream>>>(x, Wq, nullptr, q_tmp, 1);  // Q -> d_out
    gemm_kernel<<<gg, 256, 0, stream>>>(x, Wk, k_sp, nullptr, 2);   // K -> split planes
    gemm_kernel<<<gg, 256, 0, stream>>>(x, Wv, v_bf, nullptr, 0);   // V -> bf16 ws (4-pass)

    // uniform tile-partition grid: 512 blocks = exactly 2 resident per CU
    score_topk_kernel<<<512, 512, 0, stream>>>(k_sp, k_sp + SPLITSZ,
                                               k_sp + 2 * SPLITSZ,
                                               (const float*)d_out,
                                               pre, ws_val, ws_idx);

    dim3 ga(128, 2);
    merge_pv_kernel<<<ga, 256, 0, stream>>>(v_bf, mem_v, ws_val, ws_idx,
                                            post, wot, bo, (float*)d_out);
}

// Round 12
// 972.818 us; speedup vs baseline: 1.2613x; 1.0142x over previous
//
#include <hip/hip_runtime.h>
#include <hip/hip_bf16.h>

typedef unsigned short u16;
typedef unsigned int   u32;

#define BB   2
#define NN   2048
#define HS   16
#define DH   64
#define NM   16
#define JT   2064   // NM + NN
#define DIM  1024
#define JC   5      // partial top-8 slots per row (max blocks covering a row)
#define NBB  256    // blocks per batch (b)
#define TOTT 8384   // total j-tiles per batch: sum_{iy}(iy+2)

#define SPLITSZ ((size_t)BB * HS * JT * DH)   // elements per K-split plane

__device__ __forceinline__ float bfval(u16 u) { return __uint_as_float(((u32)u) << 16); }
__device__ __forceinline__ float lo16(u32 u)  { return __uint_as_float(u << 16); }
__device__ __forceinline__ float hi16(u32 u)  { return __uint_as_float(u & 0xffff0000u); }
__device__ __forceinline__ u16 f2bf(float f)
{
    __hip_bfloat16 h = __float2bfloat16(f);
    return *(u16*)&h;
}

// tile-space partition: block k (k=0..255 per b) owns tiles [start(k), start(k+1))
// start(k) = floor(131k/4)  (TOTT/NBB = 32.75 = 131/4, exact)
__device__ __forceinline__ int blk_start(int k) { return (131 * k) >> 2; }
__device__ __forceinline__ int blk_of(int g)
{
    int k = (4 * g) / 131;
    while (blk_start(k + 1) <= g) ++k;
    while (blk_start(k) > g) --k;
    return k;
}
// row (iy) starts at tile S(iy) = iy*(iy+3)/2
__device__ __forceinline__ int row_start(int iy) { return (iy * (iy + 3)) >> 1; }

typedef __bf16 bf16x8 __attribute__((ext_vector_type(8)));
typedef float  f32x4  __attribute__((ext_vector_type(4)));

#define MFMA16(A, B, C) __builtin_amdgcn_mfma_f32_16x16x32_bf16(A, B, C, 0, 0, 0)

// ---------------------------------------------------------------------------
// mem_k rows -> K-split planes (hi/mid/lo bf16) at key rows 0..15.
// ---------------------------------------------------------------------------
__global__ void prep_mem_kernel(const float* __restrict__ mem_k, u16* __restrict__ k_sp)
{
    int t = blockIdx.x * 256 + threadIdx.x;          // 0 .. 32767
    int d = t & 63, j = (t >> 6) & 15, h = (t >> 10) & 15, b = (t >> 14) & 1;
    float x = mem_k[(h * NM + j) * DH + d];
    size_t di = ((size_t)(b * HS + h) * JT + j) * DH + d;
    u16 sh = f2bf(x);
    float d1 = x - bfval(sh);
    u16 sm = f2bf(d1);
    u16 sl = f2bf(d1 - bfval(sm));
    k_sp[di] = sh; k_sp[di + SPLITSZ] = sm; k_sp[di + 2 * SPLITSZ] = sl;
}

// ---------------------------------------------------------------------------
// Wo f32 [k][n] -> WoT bf16 [n][k] (B-frag native layout for the epilogue).
// ---------------------------------------------------------------------------
__global__ void prep_wot_kernel(const float* __restrict__ Wo, u16* __restrict__ wot)
{
    int t = blockIdx.x * 256 + threadIdx.x;          // 0 .. 1048575
    int k = t & 1023, n = t >> 10;
    wot[(size_t)n * 1024 + k] = f2bf(Wo[(size_t)k * 1024 + n]);
}

// ---------------------------------------------------------------------------
// Exact-f32 GEMM via bf16 split MFMA (core verified R7-R9).
// mode 0: V -> bf16 scatter. 4-pass (mm,hm,mh,hh) — dropped hl/lh terms
//         are O(2^-16) relative, two orders below V's own bf16 rounding.
// mode 1: Q -> f32 row-major (6-pass exact: feeds score top-k, keep).
// mode 2: K -> hi/mid/lo split planes (6-pass exact).
// ---------------------------------------------------------------------------
__global__ __launch_bounds__(256) void gemm_kernel(
    const float* __restrict__ A, const float* __restrict__ Bw,
    u16* __restrict__ dst16, float* __restrict__ dstf, int mode)
{
    __shared__ __align__(16) u16 a_h[128][32];
    __shared__ __align__(16) u16 a_m[128][32];
    __shared__ __align__(16) u16 a_l[128][32];
    __shared__ __align__(16) u16 b_hT[64][32];
    __shared__ __align__(16) u16 b_mT[64][32];
    __shared__ __align__(16) u16 b_lT[64][32];

    const int tid  = threadIdx.x;
    const int m0   = blockIdx.x * 128;
    const int n0   = blockIdx.y * 64;
    const int wave = tid >> 6, lane = tid & 63;
    const int ln16 = lane & 15, quad = lane >> 4;

    const int arow = tid >> 1;            // 0..127
    const int ac   = (tid & 1) * 16;      // 0 or 16
    const int brow = tid >> 3;            // 0..31
    const int bc   = (tid & 7) * 8;       // 0..56

    f32x4 acc[8] = {};

    for (int k0 = 0; k0 < 1024; k0 += 32) {
        float av[16];
        {
            const float4* ap = (const float4*)&A[(size_t)(m0 + arow) * 1024 + k0 + ac];
            *(float4*)&av[0]  = ap[0]; *(float4*)&av[4]  = ap[1];
            *(float4*)&av[8]  = ap[2]; *(float4*)&av[12] = ap[3];
        }
        float bv[8];
        {
            const float4* bp = (const float4*)&Bw[(size_t)(k0 + brow) * 1024 + n0 + bc];
            *(float4*)&bv[0] = bp[0]; *(float4*)&bv[4] = bp[1];
        }
        u16 ah[16], am[16], al[16], bh[8], bm[8], bl[8];
        #pragma unroll
        for (int e = 0; e < 16; ++e) {
            ah[e] = f2bf(av[e]);
            float d1 = av[e] - bfval(ah[e]);
            am[e] = f2bf(d1);
            al[e] = (mode != 0) ? f2bf(d1 - bfval(am[e])) : (u16)0;
        }
        #pragma unroll
        for (int e = 0; e < 8; ++e) {
            bh[e] = f2bf(bv[e]);
            float d1 = bv[e] - bfval(bh[e]);
            bm[e] = f2bf(d1);
            bl[e] = (mode != 0) ? f2bf(d1 - bfval(bm[e])) : (u16)0;
        }
        __syncthreads();
        *(uint4*)&a_h[arow][ac]     = ((uint4*)ah)[0];
        *(uint4*)&a_h[arow][ac + 8] = ((uint4*)ah)[1];
        *(uint4*)&a_m[arow][ac]     = ((uint4*)am)[0];
        *(uint4*)&a_m[arow][ac + 8] = ((uint4*)am)[1];
        if (mode != 0) {
            *(uint4*)&a_l[arow][ac]     = ((uint4*)al)[0];
            *(uint4*)&a_l[arow][ac + 8] = ((uint4*)al)[1];
        }
        #pragma unroll
        for (int e = 0; e < 8; ++e) {
            b_hT[bc + e][brow] = bh[e];
            b_mT[bc + e][brow] = bm[e];
            if (mode != 0) b_lT[bc + e][brow] = bl[e];
        }
        __syncthreads();

        bf16x8 a0h = *(const bf16x8*)&a_h[wave * 32 + ln16][quad * 8];
        bf16x8 a0m = *(const bf16x8*)&a_m[wave * 32 + ln16][quad * 8];
        bf16x8 a1h = *(const bf16x8*)&a_h[wave * 32 + 16 + ln16][quad * 8];
        bf16x8 a1m = *(const bf16x8*)&a_m[wave * 32 + 16 + ln16][quad * 8];
        bf16x8 a0l = {}, a1l = {};
        if (mode != 0) {
            a0l = *(const bf16x8*)&a_l[wave * 32 + ln16][quad * 8];
            a1l = *(const bf16x8*)&a_l[wave * 32 + 16 + ln16][quad * 8];
        }
        #pragma unroll
        for (int c = 0; c < 4; ++c) {
            bf16x8 bh_ = *(const bf16x8*)&b_hT[c * 16 + ln16][quad * 8];
            bf16x8 bm_ = *(const bf16x8*)&b_mT[c * 16 + ln16][quad * 8];
            acc[c]     = MFMA16(a0m, bm_, acc[c]);
            acc[c]     = MFMA16(a0h, bm_, acc[c]);
            acc[c]     = MFMA16(a0m, bh_, acc[c]);
            acc[c]     = MFMA16(a0h, bh_, acc[c]);
            acc[4 + c] = MFMA16(a1m, bm_, acc[4 + c]);
            acc[4 + c] = MFMA16(a1h, bm_, acc[4 + c]);
            acc[4 + c] = MFMA16(a1m, bh_, acc[4 + c]);
            acc[4 + c] = MFMA16(a1h, bh_, acc[4 + c]);
            if (mode != 0) {
                bf16x8 bl_ = *(const bf16x8*)&b_lT[c * 16 + ln16][quad * 8];
                acc[c]     = MFMA16(a0h, bl_, acc[c]);
                acc[c]     = MFMA16(a0l, bh_, acc[c]);
                acc[4 + c] = MFMA16(a1h, bl_, acc[4 + c]);
                acc[4 + c] = MFMA16(a1l, bh_, acc[4 + c]);
            }
        }
    }

    #pragma unroll
    for (int hf = 0; hf < 2; ++hf) {
        #pragma unroll
        for (int c = 0; c < 4; ++c) {
            #pragma unroll
            for (int r = 0; r < 4; ++r) {
                int row = m0 + wave * 32 + hf * 16 + quad * 4 + r;
                int col = n0 + c * 16 + ln16;
                float v = acc[hf * 4 + c][r];
                if (mode == 1) {
                    dstf[(size_t)row * 1024 + col] = v;
                } else {
                    int b = row >> 11, i = row & 2047;
                    int hd = col >> 6, d = col & 63;
                    if (mode == 0) {
                        dst16[(((size_t)(b * HS + hd)) * NN + i) * DH + d] = f2bf(v);
                    } else {
                        size_t di = (((size_t)(b * HS + hd)) * JT + NM + i) * DH + d;
                        u16 sh = f2bf(v);
                        float d1 = v - bfval(sh);
                        u16 sm = f2bf(d1);
                        u16 sl = f2bf(d1 - bfval(sm));
                        dst16[di] = sh;
                        dst16[di + SPLITSZ] = sm;
                        dst16[di + 2 * SPLITSZ] = sl;
                    }
                }
            }
        }
    }
}

// ---------------------------------------------------------------------------
// Phase 1 (MFMA): scores + partial top-8. (== R20, measured 373 us)
// ---------------------------------------------------------------------------
__global__ __launch_bounds__(512) void score_topk_kernel(
    const u16* __restrict__ k_hi, const u16* __restrict__ k_mi,
    const u16* __restrict__ k_lo,
    const float* __restrict__ q_all, const float* __restrict__ pre,
    float* __restrict__ ws_val, u16* __restrict__ ws_idx)
{
    const int bid = blockIdx.x;                  // 0..511
    const int b   = bid >> 8;
    const int kb  = bid & 255;                   // striped: XCD = kb % 8

    int g = blk_start(kb);
    const int gend = blk_start(kb + 1);

    __shared__ __align__(16) float fsm[12544];
    float* S   = fsm;            // [2][16][256] dbuf, chunk-rotation swizzled
    float* pp  = fsm + 8192;     // [256] pre_proj * 0.125
    float* scr = fsm + 8448;     // [4096] row-flush merge scratch

    const int tid  = threadIdx.x;
    const int wave = tid >> 6, lane = tid & 63;
    const int ln16 = lane & 15, quad = lane >> 4;

    if (tid < 256) pp[tid] = pre[tid] * 0.125f;
    __syncthreads();                             // pp staged

    // scan-row ownership: waves 0-3 scan tj-half 0, waves 4-7 tj-half 1
    const int kk_r = (wave & 3) * 4 + (lane & 3);
    const int ti_r = lane >> 2;
    const int tjh  = wave >> 2;
    const int srow = kk_r * 16 + ti_r;           // scratch row id

    // u32 element offset base for this thread's K-row slice (b, lane row)
    const u32 kbase0 = ((u32)(b * HS) * JT + (u32)ln16) * DH + (u32)(quad * 8);
    const u32 hstep  = (u32)(JT * DH);           // head stride in elements
    const u32 kbA    = kbase0 + (u32)(wave * 2) * hstep;       // head wave*2
    const u32 kbB    = kbA + hstep;                            // head wave*2+1

    // initial row: largest iy with row_start(iy) <= g
    int iy = (int)((sqrtf((float)(8 * g + 9)) - 3.0f) * 0.5f);
    while (row_start(iy + 1) <= g) ++iy;
    while (row_start(iy) > g) --iy;

    // ---- prime: full prefetch of the first tile (12 loads) ----
    bf16x8 pA0h, pA0m, pA0l, pA1h, pA1m, pA1l;   // head A, halves 0/1
    bf16x8 pB0h, pB0m, pB0l, pB1h, pB1m, pB1l;   // head B, halves 0/1
    {
        const u32 j0 = (u32)((g - row_start(iy)) * 16) * DH;
        pA0h = *(const bf16x8*)(k_hi + kbA + j0);
        pA0m = *(const bf16x8*)(k_mi + kbA + j0);
        pA0l = *(const bf16x8*)(k_lo + kbA + j0);
        pA1h = *(const bf16x8*)(k_hi + kbA + j0 + 32u);
        pA1m = *(const bf16x8*)(k_mi + kbA + j0 + 32u);
        pA1l = *(const bf16x8*)(k_lo + kbA + j0 + 32u);
        pB0h = *(const bf16x8*)(k_hi + kbB + j0);
        pB0m = *(const bf16x8*)(k_mi + kbB + j0);
        pB0l = *(const bf16x8*)(k_lo + kbB + j0);
        pB1h = *(const bf16x8*)(k_hi + kbB + j0 + 32u);
        pB1m = *(const bf16x8*)(k_mi + kbB + j0 + 32u);
        pB1l = *(const bf16x8*)(k_lo + kbB + j0 + 32u);
    }

    while (g < gend) {
        const int ntiles = iy + 2;
        const int Srow0  = row_start(iy);
        int jt = g - Srow0;
        const int nrow   = min(ntiles - jt, gend - g);
        const int jt_hi  = jt + nrow;
        const int i0     = iy * 16;
        const int slot   = kb - blk_of(Srow0);

        // ---- Q A-frags for (b, iy): 2 heads/wave x 2 halves x 3 splits ----
        bf16x8 qh[2][2], qm[2][2], ql[2][2];
        {
            const float* qrow = q_all + (size_t)(b * NN + i0 + ln16) * DIM;
            #pragma unroll
            for (int h2 = 0; h2 < 2; ++h2) {
                const int h = wave * 2 + h2;
                #pragma unroll
                for (int half = 0; half < 2; ++half) {
                    const float* src = qrow + h * 64 + half * 32 + quad * 8;
                    float4 u0 = *(const float4*)src;
                    float4 u1 = *(const float4*)(src + 4);
                    float xv[8] = {u0.x, u0.y, u0.z, u0.w, u1.x, u1.y, u1.z, u1.w};
                    u16 eh[8], em[8], el[8];
                    #pragma unroll
                    for (int e = 0; e < 8; ++e) {
                        eh[e] = f2bf(xv[e]);
                        float d1 = xv[e] - bfval(eh[e]);
                        em[e] = f2bf(d1);
                        el[e] = f2bf(d1 - bfval(em[e]));
                    }
                    qh[h2][half] = *(bf16x8*)eh;
                    qm[h2][half] = *(bf16x8*)em;
                    ql[h2][half] = *(bf16x8*)el;
                }
            }
        }

        float tv[8];
        int   tx[8];
        #pragma unroll
        for (int t = 0; t < 8; ++t) { tv[t] = -1e30f; tx[t] = 0; }
        const int jlim = NM + i0 + ti_r;

        int par = 0;
        for (; jt < jt_hi; ++jt, par ^= 1) {
            float* Sb = S + par * 4096;

            {   // ---- head A (wave*2): all operands prefetched ----
                f32x4 acc = {};
                acc = MFMA16(qm[0][0], pA0m, acc);
                acc = MFMA16(qh[0][0], pA0l, acc);
                acc = MFMA16(ql[0][0], pA0h, acc);
                acc = MFMA16(qh[0][0], pA0m, acc);
                acc = MFMA16(qm[0][0], pA0h, acc);
                acc = MFMA16(qh[0][0], pA0h, acc);
                acc = MFMA16(qm[0][1], pA1m, acc);
                acc = MFMA16(qh[0][1], pA1l, acc);
                acc = MFMA16(ql[0][1], pA1h, acc);
                acc = MFMA16(qh[0][1], pA1m, acc);
                acc = MFMA16(qm[0][1], pA1h, acc);
                acc = MFMA16(qh[0][1], pA1h, acc);
                const int h = wave * 2;
                #pragma unroll
                for (int r = 0; r < 4; ++r) {
                    int i   = quad * 4 + r;
                    int rot = ((ln16 >> 2) + i + (i >> 2)) & 3;
                    Sb[h * 256 + i * 16 + rot * 4 + (ln16 & 3)] = acc[r];
                }
            }
            {   // ---- head B (wave*2+1) ----
                f32x4 acc = {};
                acc = MFMA16(qm[1][0], pB0m, acc);
                acc = MFMA16(qh[1][0], pB0l, acc);
                acc = MFMA16(ql[1][0], pB0h, acc);
                acc = MFMA16(qh[1][0], pB0m, acc);
                acc = MFMA16(qm[1][0], pB0h, acc);
                acc = MFMA16(qh[1][0], pB0h, acc);
                acc = MFMA16(qm[1][1], pB1m, acc);
                acc = MFMA16(qh[1][1], pB1l, acc);
                acc = MFMA16(ql[1][1], pB1h, acc);
                acc = MFMA16(qh[1][1], pB1m, acc);
                acc = MFMA16(qm[1][1], pB1h, acc);
                acc = MFMA16(qh[1][1], pB1h, acc);
                const int h = wave * 2 + 1;
                #pragma unroll
                for (int r = 0; r < 4; ++r) {
                    int i   = quad * 4 + r;
                    int rot = ((ln16 >> 2) + i + (i >> 2)) & 3;
                    Sb[h * 256 + i * 16 + rot * 4 + (ln16 & 3)] = acc[r];
                }
            }

            // ---- full prefetch of next tile (cross-row continuous):
            // K addr depends only on jt; next row starts at jt=0.
            {
                const int jt_next = (jt + 1 < jt_hi) ? jt + 1 : 0;
                const u32 jn = (u32)(jt_next * 16) * DH;
                pA0h = *(const bf16x8*)(k_hi + kbA + jn);
                pA0m = *(const bf16x8*)(k_mi + kbA + jn);
                pA0l = *(const bf16x8*)(k_lo + kbA + jn);
                pA1h = *(const bf16x8*)(k_hi + kbA + jn + 32u);
                pA1m = *(const bf16x8*)(k_mi + kbA + jn + 32u);
                pA1l = *(const bf16x8*)(k_lo + kbA + jn + 32u);
                pB0h = *(const bf16x8*)(k_hi + kbB + jn);
                pB0m = *(const bf16x8*)(k_mi + kbB + jn);
                pB0l = *(const bf16x8*)(k_lo + kbB + jn);
                pB1h = *(const bf16x8*)(k_hi + kbB + jn + 32u);
                pB1m = *(const bf16x8*)(k_mi + kbB + jn + 32u);
                pB1l = *(const bf16x8*)(k_lo + kbB + jn + 32u);
            }

            // ---- LDS handoff WITHOUT vmcnt drain ----
            asm volatile("s_waitcnt lgkmcnt(0)" ::: "memory");
            __builtin_amdgcn_s_barrier();
            __builtin_amdgcn_sched_barrier(0);   // pin: no mix-read hoisting

            // fused mix+scan for row (kk_r, ti_r), tj chunks {2*tjh, 2*tjh+1}
            const int jb = jt * 16;
            #pragma unroll
            for (int tc = 0; tc < 2; ++tc) {
                const int tjc = tjh * 2 + tc;
                const int rot = (tjc + ti_r + (ti_r >> 2)) & 3;
                const float* sp = Sb + ti_r * 16 + rot * 4;
                f32x4 m = {};
                #pragma unroll
                for (int h = 0; h < 16; ++h) {
                    float w  = pp[h * 16 + kk_r];             // broadcast b32
                    f32x4 s4 = *(const f32x4*)(sp + h * 256); // 4-way bcast b128
                    m += s4 * w;                              // v_pk_fma_f32 x2
                }
                const int jb2 = jb + tjc * 4;
                #pragma unroll
                for (int e = 0; e < 4; ++e) {
                    float c = m[e];
                    int j = jb2 + e;
                    if (j <= jlim && c > tv[7]) {
                        #pragma unroll
                        for (int t = 7; t >= 1; --t) {
                            if (c > tv[t - 1])      { tv[t] = tv[t - 1]; tx[t] = tx[t - 1]; }
                            else if (c > tv[t])     { tv[t] = c;         tx[t] = j; }
                        }
                        if (c > tv[0]) { tv[0] = c; tx[0] = j; }
                    }
                }
            }
            // no trailing barrier: next tile writes the other S buffer; the
            // per-tile barrier above orders reads(t) before writes(t+2).
        }

        // ---- row flush: merge tj-halves, write ws slot ----
        __syncthreads();                         // all scans for this row done
        if (tjh == 1) {
            #pragma unroll
            for (int t = 0; t < 8; ++t) {
                scr[srow * 8 + t]        = tv[t];
                scr[2048 + srow * 8 + t] = __int_as_float(tx[t]);
            }
        }
        __syncthreads();
        if (tjh == 0) {
            #pragma unroll
            for (int t2 = 0; t2 < 8; ++t2) {
                float c = scr[srow * 8 + t2];
                int   j = __float_as_int(scr[2048 + srow * 8 + t2]);
                if (c > tv[7]) {
                    #pragma unroll
                    for (int t = 7; t >= 1; --t) {
                        if (c > tv[t - 1])      { tv[t] = tv[t - 1]; tx[t] = tx[t - 1]; }
                        else if (c > tv[t])     { tv[t] = c;         tx[t] = j; }
                    }
                    if (c > tv[0]) { tv[0] = c; tx[0] = j; }
                }
            }
            size_t base = ((((size_t)b * HS + kk_r) * NN + i0 + ti_r) * JC + slot) * 8;
            #pragma unroll
            for (int t = 0; t < 8; ++t) {
                ws_val[base + t] = tv[t];
                ws_idx[base + t] = (u16)tx[t];
            }
        }

        g += nrow;
        ++iy;                                    // valid when row exhausted;
    }                                            // otherwise g==gend -> exit
}

// ---------------------------------------------------------------------------
// Phase 2: merge partial top-8s -> softmax -> sparse PV -> fused out-proj.
// R21: 512 threads (was 256 = 1 wave/SIMD, zero latency hiding):
//   - merge+softmax: threads 0-255 (guarded, brief).
//   - PV: thread = (dh, ti_o, k2), dh = tid>>8 splits d-dim -> acc[32],
//     half the serial load/FMA chain per thread.
//   - out-proj: 8 waves x 8 n-tiles (n = (t8*8+wave)*16+ln16, bijective),
//     oacc[8] per thread.
// Semantics identical; concurrency 2x.
// ---------------------------------------------------------------------------
__global__ __launch_bounds__(512) void merge_pv_kernel(
    const u16* __restrict__ v_bf, const float* __restrict__ mem_v,
    const float* __restrict__ ws_val, const u16* __restrict__ ws_idx,
    const float* __restrict__ post, const u16* __restrict__ wot,
    const float* __restrict__ bo, float* __restrict__ out)
{
    __shared__ __align__(16) float fsm[13312];
    float* dotsm = fsm + 8704;     // [4096]: w park [0..2047], j park [2048..4095]
    float* pp2   = fsm + 13056;    // [256] post_proj
    u16*   arows = (u16*)fsm;      // [16][1032] bf16 (PV rows)

    const int tid = threadIdx.x;
    const int b   = blockIdx.y;
    const int i0  = blockIdx.x * 16;
    const int ntiles = blockIdx.x + 2;
    const int Srow0  = row_start(blockIdx.x);
    const int jc_cnt = blk_of(Srow0 + ntiles - 1) - blk_of(Srow0) + 1;

    if (tid < 256) pp2[tid] = post[tid];

    // ---- phase 1 (threads 0-255): top-8 merge + softmax -> dotsm ----
    if (tid < 256) {
        const int kk_r = tid & 15, ti_r = tid >> 4;

        float tv[8];
        int   tx[8];
        #pragma unroll
        for (int t = 0; t < 8; ++t) { tv[t] = -1e30f; tx[t] = 0; }

        size_t rbase = (((size_t)b * HS + kk_r) * NN + i0 + ti_r) * JC;
        for (int jc = 0; jc < jc_cnt; ++jc) {
            #pragma unroll
            for (int t2 = 0; t2 < 8; ++t2) {
                float c = ws_val[(rbase + jc) * 8 + t2];
                int   j = ws_idx[(rbase + jc) * 8 + t2];
                if (c > tv[7]) {
                    #pragma unroll
                    for (int t = 7; t >= 1; --t) {
                        if (c > tv[t - 1])      { tv[t] = tv[t - 1]; tx[t] = tx[t - 1]; }
                        else if (c > tv[t])     { tv[t] = c;         tx[t] = j; }
                    }
                    if (c > tv[0]) { tv[0] = c; tx[0] = j; }
                }
            }
        }

        float m = tv[0];
        float wv[8], wsum = 0.f;
        #pragma unroll
        for (int t = 0; t < 8; ++t) { wv[t] = __expf(tv[t] - m); wsum += wv[t]; }
        float inv = 1.f / wsum;

        #pragma unroll
        for (int t = 0; t < 8; ++t) {
            dotsm[(kk_r * 16 + ti_r) * 8 + t]        = wv[t] * inv;
            dotsm[2048 + (kk_r * 16 + ti_r) * 8 + t] = __int_as_float(tx[t]);
        }
    }
    __syncthreads();

    // ---- phase 2 PV: thread = (dh, ti_o, k2); dh splits the d-dimension ----
    {
        const int ti_o = (tid & 255) >> 4, k2 = tid & 15, dh = tid >> 8;
        float acc[32];
        #pragma unroll
        for (int d = 0; d < 32; ++d) acc[d] = 0.f;
        const u16*   vws_base  = v_bf + (size_t)(b * HS + k2) * NN * DH + dh * 32;
        const float* vmem_base = mem_v + (size_t)k2 * NM * DH + dh * 32;

        for (int kk = 0; kk < 16; ++kk) {
            float p2 = pp2[kk * 16 + k2];
            for (int t = 0; t < 8; ++t) {
                float w = dotsm[(kk * 16 + ti_o) * 8 + t] * p2;
                int j = __float_as_int(dotsm[2048 + (kk * 16 + ti_o) * 8 + t]);
                if (j < NM) {
                    const float* vr = vmem_base + (size_t)j * DH;
                    #pragma unroll
                    for (int r = 0; r < 8; ++r) {
                        float4 u = *(const float4*)&vr[r * 4];
                        acc[r * 4 + 0] += w * u.x; acc[r * 4 + 1] += w * u.y;
                        acc[r * 4 + 2] += w * u.z; acc[r * 4 + 3] += w * u.w;
                    }
                } else {
                    const uint4* vr = (const uint4*)(vws_base + (size_t)(j - NM) * DH);
                    #pragma unroll
                    for (int r = 0; r < 4; ++r) {
                        uint4 u = vr[r];
                        acc[r * 8 + 0] += w * lo16(u.x); acc[r * 8 + 1] += w * hi16(u.x);
                        acc[r * 8 + 2] += w * lo16(u.y); acc[r * 8 + 3] += w * hi16(u.y);
                        acc[r * 8 + 4] += w * lo16(u.z); acc[r * 8 + 5] += w * hi16(u.z);
                        acc[r * 8 + 6] += w * lo16(u.w); acc[r * 8 + 7] += w * hi16(u.w);
                    }
                }
            }
        }
        #pragma unroll
        for (int d = 0; d < 32; ++d) {
            float o = acc[d];
            o = (o == o) ? o : 1e4f;             // V-side NaN sentinel (diagnostic)
            arows[ti_o * 1032 + k2 * 64 + dh * 32 + d] = f2bf(o);
        }
    }
    __syncthreads();

    // ---- phase 3 out-proj: 8 waves, n = (t8*8 + wave)*16 + ln16 ----
    const int wave = tid >> 6, lane = tid & 63;
    const int ln16 = lane & 15, quad = lane >> 4;

    f32x4 oacc[8];
    #pragma unroll
    for (int t = 0; t < 8; ++t) {
        float bv = bo[(t * 8 + wave) * 16 + ln16];
        oacc[t][0] = bv; oacc[t][1] = bv; oacc[t][2] = bv; oacc[t][3] = bv;
    }

    for (int k0 = 0; k0 < 1024; k0 += 32) {
        bf16x8 af = *(const bf16x8*)&arows[ln16 * 1032 + k0 + quad * 8];
        #pragma unroll
        for (int t = 0; t < 8; ++t) {
            const int n = (t * 8 + wave) * 16 + ln16;
            bf16x8 bf_ = *(const bf16x8*)&wot[(size_t)n * 1024 + k0 + quad * 8];
            oacc[t] = MFMA16(af, bf_, oacc[t]);
        }
    }

    #pragma unroll
    for (int t = 0; t < 8; ++t) {
        const int n = (t * 8 + wave) * 16 + ln16;
        #pragma unroll
        for (int r = 0; r < 4; ++r) {
            int row = quad * 4 + r;
            out[(size_t)(b * NN + i0 + row) * DIM + n] = oacc[t][r];
        }
    }
}

// ---------------------------------------------------------------------------
extern "C" void kernel_launch(void* const* d_in, const int* in_sizes, int n_in,
                              void* d_out, int out_size, void* d_ws, size_t ws_size,
                              hipStream_t stream)
{
    (void)in_sizes; (void)n_in; (void)out_size; (void)ws_size;
    const float* x     = (const float*)d_in[0];
    const float* Wq    = (const float*)d_in[1];
    const float* Wk    = (const float*)d_in[2];
    const float* Wv    = (const float*)d_in[3];
    const float* pre   = (const float*)d_in[4];
    const float* post  = (const float*)d_in[5];
    const float* mem_k = (const float*)d_in[6];
    const float* mem_v = (const float*)d_in[7];
    const float* Wo    = (const float*)d_in[8];
    const float* bo    = (const float*)d_in[9];

    // workspace (51.6 MB total, < 54.6 proven):
    //   K splits 3x bf16 [2][16][2064][64]            = 25.36 MB
    //   V bf16 [2][16][2048][64]                      =  8.39 MB
    //   partial top-8 val f32 [2][16][2048][JC=5][8]  = 10.49 MB
    //   partial top-8 idx u16                          =  5.24 MB
    //   WoT bf16 [1024][1024]                         =  2.10 MB
    u16*   k_sp   = (u16*)d_ws;
    u16*   v_bf   = k_sp + 3 * SPLITSZ;
    float* ws_val = (float*)(v_bf + (size_t)BB * HS * NN * DH);
    u16*   ws_idx = (u16*)(ws_val + (size_t)BB * HS * NN * JC * 8);
    u16*   wot    = ws_idx + (size_t)BB * HS * NN * JC * 8;
    float* q_tmp  = (float*)d_out;                           // Q f32 [b*n][1024]

    prep_mem_kernel<<<128, 256, 0, stream>>>(mem_k, k_sp);
    prep_wot_kernel<<<4096, 256, 0, stream>>>(Wo, wot);

    dim3 gg(32, 16);
    gemm_kernel<<<gg, 256, 0, stream>>>(x, Wq, nullptr, q_tmp, 1);  // Q -> d_out
    gemm_kernel<<<gg, 256, 0, stream>>>(x, Wk, k_sp, nullptr, 2);   // K -> split planes
    gemm_kernel<<<gg, 256, 0, stream>>>(x, Wv, v_bf, nullptr, 0);   // V -> bf16 ws (4-pass)

    // uniform tile-partition grid: 512 blocks = exactly 2 resident per CU
    score_topk_kernel<<<512, 512, 0, stream>>>(k_sp, k_sp + SPLITSZ,
                                               k_sp + 2 * SPLITSZ,
                                               (const float*)d_out,
                                               pre, ws_val, ws_idx);

    dim3 ga(128, 2);
    merge_pv_kernel<<<ga, 512, 0, stream>>>(v_bf, mem_v, ws_val, ws_idx,
                                            post, wot, bo, (float*)d_out);
}

// Round 13
// 962.251 us; speedup vs baseline: 1.2752x; 1.0110x over previous
//
#include <hip/hip_runtime.h>
#include <hip/hip_bf16.h>

typedef unsigned short u16;
typedef unsigned int   u32;

#define BB   2
#define NN   2048
#define HS   16
#define DH   64
#define NM   16
#define JT   2064   // NM + NN
#define DIM  1024
#define JC   5      // partial top-8 slots per row (max blocks covering a row)
#define NBB  256    // blocks per batch (b)
#define TOTT 8384   // total j-tiles per batch: sum_{iy}(iy+2)

#define SPLITSZ ((size_t)BB * HS * JT * DH)   // elements per K-split plane

__device__ __forceinline__ float bfval(u16 u) { return __uint_as_float(((u32)u) << 16); }
__device__ __forceinline__ float lo16(u32 u)  { return __uint_as_float(u << 16); }
__device__ __forceinline__ float hi16(u32 u)  { return __uint_as_float(u & 0xffff0000u); }
__device__ __forceinline__ u16 f2bf(float f)
{
    __hip_bfloat16 h = __float2bfloat16(f);
    return *(u16*)&h;
}

// tile-space partition: block k (k=0..255 per b) owns tiles [start(k), start(k+1))
// start(k) = floor(131k/4)  (TOTT/NBB = 32.75 = 131/4, exact)
__device__ __forceinline__ int blk_start(int k) { return (131 * k) >> 2; }
__device__ __forceinline__ int blk_of(int g)
{
    int k = (4 * g) / 131;
    while (blk_start(k + 1) <= g) ++k;
    while (blk_start(k) > g) --k;
    return k;
}
// row (iy) starts at tile S(iy) = iy*(iy+3)/2
__device__ __forceinline__ int row_start(int iy) { return (iy * (iy + 3)) >> 1; }

typedef __bf16 bf16x8 __attribute__((ext_vector_type(8)));
typedef float  f32x4  __attribute__((ext_vector_type(4)));

#define MFMA16(A, B, C) __builtin_amdgcn_mfma_f32_16x16x32_bf16(A, B, C, 0, 0, 0)

// ---------------------------------------------------------------------------
// mem_k rows -> K-split planes (hi/mid/lo bf16) at key rows 0..15.
// ---------------------------------------------------------------------------
__global__ void prep_mem_kernel(const float* __restrict__ mem_k, u16* __restrict__ k_sp)
{
    int t = blockIdx.x * 256 + threadIdx.x;          // 0 .. 32767
    int d = t & 63, j = (t >> 6) & 15, h = (t >> 10) & 15, b = (t >> 14) & 1;
    float x = mem_k[(h * NM + j) * DH + d];
    size_t di = ((size_t)(b * HS + h) * JT + j) * DH + d;
    u16 sh = f2bf(x);
    float d1 = x - bfval(sh);
    u16 sm = f2bf(d1);
    u16 sl = f2bf(d1 - bfval(sm));
    k_sp[di] = sh; k_sp[di + SPLITSZ] = sm; k_sp[di + 2 * SPLITSZ] = sl;
}

// ---------------------------------------------------------------------------
// Wo f32 [k][n] -> WoT bf16 [n][k].
// R22: 32x32 LDS tile transpose — coalesced reads AND writes (old version
// read Wo at stride 4KB: 64x over-fetch per wave).
// ---------------------------------------------------------------------------
__global__ __launch_bounds__(256) void prep_wot_kernel(
    const float* __restrict__ Wo, u16* __restrict__ wot)
{
    __shared__ u16 t[32][33];
    const int bx = blockIdx.x & 31;          // n-tile
    const int by = blockIdx.x >> 5;          // k-tile
    const int tx = threadIdx.x & 31, ty = threadIdx.x >> 5;   // 32 x 8

    #pragma unroll
    for (int i = 0; i < 32; i += 8)          // t[k_local][n_local]
        t[ty + i][tx] = f2bf(Wo[(size_t)(by * 32 + ty + i) * 1024 + bx * 32 + tx]);
    __syncthreads();
    #pragma unroll
    for (int i = 0; i < 32; i += 8)          // wot[n][k] = t[k_local=tx][n_local=ty+i]
        wot[(size_t)(bx * 32 + ty + i) * 1024 + by * 32 + tx] = t[tx][ty + i];
}

// ---------------------------------------------------------------------------
// Exact-f32 GEMM via bf16 split MFMA (core verified R7-R9).
// mode 0: V -> bf16 scatter (4-pass). mode 1: Q -> f32 (6-pass).
// mode 2: K -> hi/mid/lo split planes (6-pass).
// R22: cross-barrier pipelined K-loop (R17/R20 idiom): next iter's A/B f32
// loads are issued AFTER the LDS writes and stay in flight across the raw
// barrier + MFMA phase (a __syncthreads would drain vmcnt -> serial latency
// per iter). Numerically identical: same loads, same cvt, same MFMA order.
// ---------------------------------------------------------------------------
__global__ __launch_bounds__(256) void gemm_kernel(
    const float* __restrict__ A, const float* __restrict__ Bw,
    u16* __restrict__ dst16, float* __restrict__ dstf, int mode)
{
    __shared__ __align__(16) u16 a_h[128][32];
    __shared__ __align__(16) u16 a_m[128][32];
    __shared__ __align__(16) u16 a_l[128][32];
    __shared__ __align__(16) u16 b_hT[64][32];
    __shared__ __align__(16) u16 b_mT[64][32];
    __shared__ __align__(16) u16 b_lT[64][32];

    const int tid  = threadIdx.x;
    const int m0   = blockIdx.x * 128;
    const int n0   = blockIdx.y * 64;
    const int wave = tid >> 6, lane = tid & 63;
    const int ln16 = lane & 15, quad = lane >> 4;

    const int arow = tid >> 1;            // 0..127
    const int ac   = (tid & 1) * 16;      // 0 or 16
    const int brow = tid >> 3;            // 0..31
    const int bc   = (tid & 7) * 8;       // 0..56

    const float* aptr = &A[(size_t)(m0 + arow) * 1024 + ac];
    const float* bptr = &Bw[(size_t)brow * 1024 + n0 + bc];

    f32x4 acc[8] = {};

    // prologue: load k0 = 0
    float av[16], bv[8];
    {
        const float4* ap = (const float4*)aptr;
        *(float4*)&av[0]  = ap[0]; *(float4*)&av[4]  = ap[1];
        *(float4*)&av[8]  = ap[2]; *(float4*)&av[12] = ap[3];
        const float4* bp = (const float4*)bptr;
        *(float4*)&bv[0] = bp[0]; *(float4*)&bv[4] = bp[1];
    }

    for (int k0 = 0; k0 < 1024; k0 += 32) {
        // cvt this iter's staged registers
        u16 ah[16], am[16], al[16], bh[8], bm[8], bl[8];
        #pragma unroll
        for (int e = 0; e < 16; ++e) {
            ah[e] = f2bf(av[e]);
            float d1 = av[e] - bfval(ah[e]);
            am[e] = f2bf(d1);
            al[e] = (mode != 0) ? f2bf(d1 - bfval(am[e])) : (u16)0;
        }
        #pragma unroll
        for (int e = 0; e < 8; ++e) {
            bh[e] = f2bf(bv[e]);
            float d1 = bv[e] - bfval(bh[e]);
            bm[e] = f2bf(d1);
            bl[e] = (mode != 0) ? f2bf(d1 - bfval(bm[e])) : (u16)0;
        }

        // barrier 1: previous iter's LDS reads complete (lgkm only — no vmcnt)
        asm volatile("s_waitcnt lgkmcnt(0)" ::: "memory");
        __builtin_amdgcn_s_barrier();

        *(uint4*)&a_h[arow][ac]     = ((uint4*)ah)[0];
        *(uint4*)&a_h[arow][ac + 8] = ((uint4*)ah)[1];
        *(uint4*)&a_m[arow][ac]     = ((uint4*)am)[0];
        *(uint4*)&a_m[arow][ac + 8] = ((uint4*)am)[1];
        if (mode != 0) {
            *(uint4*)&a_l[arow][ac]     = ((uint4*)al)[0];
            *(uint4*)&a_l[arow][ac + 8] = ((uint4*)al)[1];
        }
        #pragma unroll
        for (int e = 0; e < 8; ++e) {
            b_hT[bc + e][brow] = bh[e];
            b_mT[bc + e][brow] = bm[e];
            if (mode != 0) b_lT[bc + e][brow] = bl[e];
        }

        // issue next iter's loads — stay in flight across barrier + MFMAs
        {
            const int kn = (k0 + 32 < 1024) ? k0 + 32 : 0;   // uniform clamp
            const float4* ap = (const float4*)(aptr + kn);
            *(float4*)&av[0]  = ap[0]; *(float4*)&av[4]  = ap[1];
            *(float4*)&av[8]  = ap[2]; *(float4*)&av[12] = ap[3];
            const float4* bp = (const float4*)(bptr + (size_t)kn * 1024);
            *(float4*)&bv[0] = bp[0]; *(float4*)&bv[4] = bp[1];
        }

        // barrier 2: LDS writes visible (lgkm only — vmcnt prefetch survives)
        asm volatile("s_waitcnt lgkmcnt(0)" ::: "memory");
        __builtin_amdgcn_s_barrier();
        __builtin_amdgcn_sched_barrier(0);

        bf16x8 a0h = *(const bf16x8*)&a_h[wave * 32 + ln16][quad * 8];
        bf16x8 a0m = *(const bf16x8*)&a_m[wave * 32 + ln16][quad * 8];
        bf16x8 a1h = *(const bf16x8*)&a_h[wave * 32 + 16 + ln16][quad * 8];
        bf16x8 a1m = *(const bf16x8*)&a_m[wave * 32 + 16 + ln16][quad * 8];
        bf16x8 a0l = {}, a1l = {};
        if (mode != 0) {
            a0l = *(const bf16x8*)&a_l[wave * 32 + ln16][quad * 8];
            a1l = *(const bf16x8*)&a_l[wave * 32 + 16 + ln16][quad * 8];
        }
        #pragma unroll
        for (int c = 0; c < 4; ++c) {
            bf16x8 bh_ = *(const bf16x8*)&b_hT[c * 16 + ln16][quad * 8];
            bf16x8 bm_ = *(const bf16x8*)&b_mT[c * 16 + ln16][quad * 8];
            acc[c]     = MFMA16(a0m, bm_, acc[c]);
            acc[c]     = MFMA16(a0h, bm_, acc[c]);
            acc[c]     = MFMA16(a0m, bh_, acc[c]);
            acc[c]     = MFMA16(a0h, bh_, acc[c]);
            acc[4 + c] = MFMA16(a1m, bm_, acc[4 + c]);
            acc[4 + c] = MFMA16(a1h, bm_, acc[4 + c]);
            acc[4 + c] = MFMA16(a1m, bh_, acc[4 + c]);
            acc[4 + c] = MFMA16(a1h, bh_, acc[4 + c]);
            if (mode != 0) {
                bf16x8 bl_ = *(const bf16x8*)&b_lT[c * 16 + ln16][quad * 8];
                acc[c]     = MFMA16(a0h, bl_, acc[c]);
                acc[c]     = MFMA16(a0l, bh_, acc[c]);
                acc[4 + c] = MFMA16(a1h, bl_, acc[4 + c]);
                acc[4 + c] = MFMA16(a1l, bh_, acc[4 + c]);
            }
        }
    }

    #pragma unroll
    for (int hf = 0; hf < 2; ++hf) {
        #pragma unroll
        for (int c = 0; c < 4; ++c) {
            #pragma unroll
            for (int r = 0; r < 4; ++r) {
                int row = m0 + wave * 32 + hf * 16 + quad * 4 + r;
                int col = n0 + c * 16 + ln16;
                float v = acc[hf * 4 + c][r];
                if (mode == 1) {
                    dstf[(size_t)row * 1024 + col] = v;
                } else {
                    int b = row >> 11, i = row & 2047;
                    int hd = col >> 6, d = col & 63;
                    if (mode == 0) {
                        dst16[(((size_t)(b * HS + hd)) * NN + i) * DH + d] = f2bf(v);
                    } else {
                        size_t di = (((size_t)(b * HS + hd)) * JT + NM + i) * DH + d;
                        u16 sh = f2bf(v);
                        float d1 = v - bfval(sh);
                        u16 sm = f2bf(d1);
                        u16 sl = f2bf(d1 - bfval(sm));
                        dst16[di] = sh;
                        dst16[di + SPLITSZ] = sm;
                        dst16[di + 2 * SPLITSZ] = sl;
                    }
                }
            }
        }
    }
}

// ---------------------------------------------------------------------------
// Phase 1 (MFMA): scores + partial top-8. (== R20, measured 373-374 us)
// ---------------------------------------------------------------------------
__global__ __launch_bounds__(512) void score_topk_kernel(
    const u16* __restrict__ k_hi, const u16* __restrict__ k_mi,
    const u16* __restrict__ k_lo,
    const float* __restrict__ q_all, const float* __restrict__ pre,
    float* __restrict__ ws_val, u16* __restrict__ ws_idx)
{
    const int bid = blockIdx.x;                  // 0..511
    const int b   = bid >> 8;
    const int kb  = bid & 255;                   // striped: XCD = kb % 8

    int g = blk_start(kb);
    const int gend = blk_start(kb + 1);

    __shared__ __align__(16) float fsm[12544];
    float* S   = fsm;            // [2][16][256] dbuf, chunk-rotation swizzled
    float* pp  = fsm + 8192;     // [256] pre_proj * 0.125
    float* scr = fsm + 8448;     // [4096] row-flush merge scratch

    const int tid  = threadIdx.x;
    const int wave = tid >> 6, lane = tid & 63;
    const int ln16 = lane & 15, quad = lane >> 4;

    if (tid < 256) pp[tid] = pre[tid] * 0.125f;
    __syncthreads();                             // pp staged

    // scan-row ownership: waves 0-3 scan tj-half 0, waves 4-7 tj-half 1
    const int kk_r = (wave & 3) * 4 + (lane & 3);
    const int ti_r = lane >> 2;
    const int tjh  = wave >> 2;
    const int srow = kk_r * 16 + ti_r;           // scratch row id

    // u32 element offset base for this thread's K-row slice (b, lane row)
    const u32 kbase0 = ((u32)(b * HS) * JT + (u32)ln16) * DH + (u32)(quad * 8);
    const u32 hstep  = (u32)(JT * DH);           // head stride in elements
    const u32 kbA    = kbase0 + (u32)(wave * 2) * hstep;       // head wave*2
    const u32 kbB    = kbA + hstep;                            // head wave*2+1

    // initial row: largest iy with row_start(iy) <= g
    int iy = (int)((sqrtf((float)(8 * g + 9)) - 3.0f) * 0.5f);
    while (row_start(iy + 1) <= g) ++iy;
    while (row_start(iy) > g) --iy;

    // ---- prime: full prefetch of the first tile (12 loads) ----
    bf16x8 pA0h, pA0m, pA0l, pA1h, pA1m, pA1l;   // head A, halves 0/1
    bf16x8 pB0h, pB0m, pB0l, pB1h, pB1m, pB1l;   // head B, halves 0/1
    {
        const u32 j0 = (u32)((g - row_start(iy)) * 16) * DH;
        pA0h = *(const bf16x8*)(k_hi + kbA + j0);
        pA0m = *(const bf16x8*)(k_mi + kbA + j0);
        pA0l = *(const bf16x8*)(k_lo + kbA + j0);
        pA1h = *(const bf16x8*)(k_hi + kbA + j0 + 32u);
        pA1m = *(const bf16x8*)(k_mi + kbA + j0 + 32u);
        pA1l = *(const bf16x8*)(k_lo + kbA + j0 + 32u);
        pB0h = *(const bf16x8*)(k_hi + kbB + j0);
        pB0m = *(const bf16x8*)(k_mi + kbB + j0);
        pB0l = *(const bf16x8*)(k_lo + kbB + j0);
        pB1h = *(const bf16x8*)(k_hi + kbB + j0 + 32u);
        pB1m = *(const bf16x8*)(k_mi + kbB + j0 + 32u);
        pB1l = *(const bf16x8*)(k_lo + kbB + j0 + 32u);
    }

    while (g < gend) {
        const int ntiles = iy + 2;
        const int Srow0  = row_start(iy);
        int jt = g - Srow0;
        const int nrow   = min(ntiles - jt, gend - g);
        const int jt_hi  = jt + nrow;
        const int i0     = iy * 16;
        const int slot   = kb - blk_of(Srow0);

        // ---- Q A-frags for (b, iy): 2 heads/wave x 2 halves x 3 splits ----
        bf16x8 qh[2][2], qm[2][2], ql[2][2];
        {
            const float* qrow = q_all + (size_t)(b * NN + i0 + ln16) * DIM;
            #pragma unroll
            for (int h2 = 0; h2 < 2; ++h2) {
                const int h = wave * 2 + h2;
                #pragma unroll
                for (int half = 0; half < 2; ++half) {
                    const float* src = qrow + h * 64 + half * 32 + quad * 8;
                    float4 u0 = *(const float4*)src;
                    float4 u1 = *(const float4*)(src + 4);
                    float xv[8] = {u0.x, u0.y, u0.z, u0.w, u1.x, u1.y, u1.z, u1.w};
                    u16 eh[8], em[8], el[8];
                    #pragma unroll
                    for (int e = 0; e < 8; ++e) {
                        eh[e] = f2bf(xv[e]);
                        float d1 = xv[e] - bfval(eh[e]);
                        em[e] = f2bf(d1);
                        el[e] = f2bf(d1 - bfval(em[e]));
                    }
                    qh[h2][half] = *(bf16x8*)eh;
                    qm[h2][half] = *(bf16x8*)em;
                    ql[h2][half] = *(bf16x8*)el;
                }
            }
        }

        float tv[8];
        int   tx[8];
        #pragma unroll
        for (int t = 0; t < 8; ++t) { tv[t] = -1e30f; tx[t] = 0; }
        const int jlim = NM + i0 + ti_r;

        int par = 0;
        for (; jt < jt_hi; ++jt, par ^= 1) {
            float* Sb = S + par * 4096;

            {   // ---- head A (wave*2): all operands prefetched ----
                f32x4 acc = {};
                acc = MFMA16(qm[0][0], pA0m, acc);
                acc = MFMA16(qh[0][0], pA0l, acc);
                acc = MFMA16(ql[0][0], pA0h, acc);
                acc = MFMA16(qh[0][0], pA0m, acc);
                acc = MFMA16(qm[0][0], pA0h, acc);
                acc = MFMA16(qh[0][0], pA0h, acc);
                acc = MFMA16(qm[0][1], pA1m, acc);
                acc = MFMA16(qh[0][1], pA1l, acc);
                acc = MFMA16(ql[0][1], pA1h, acc);
                acc = MFMA16(qh[0][1], pA1m, acc);
                acc = MFMA16(qm[0][1], pA1h, acc);
                acc = MFMA16(qh[0][1], pA1h, acc);
                const int h = wave * 2;
                #pragma unroll
                for (int r = 0; r < 4; ++r) {
                    int i   = quad * 4 + r;
                    int rot = ((ln16 >> 2) + i + (i >> 2)) & 3;
                    Sb[h * 256 + i * 16 + rot * 4 + (ln16 & 3)] = acc[r];
                }
            }
            {   // ---- head B (wave*2+1) ----
                f32x4 acc = {};
                acc = MFMA16(qm[1][0], pB0m, acc);
                acc = MFMA16(qh[1][0], pB0l, acc);
                acc = MFMA16(ql[1][0], pB0h, acc);
                acc = MFMA16(qh[1][0], pB0m, acc);
                acc = MFMA16(qm[1][0], pB0h, acc);
                acc = MFMA16(qh[1][0], pB0h, acc);
                acc = MFMA16(qm[1][1], pB1m, acc);
                acc = MFMA16(qh[1][1], pB1l, acc);
                acc = MFMA16(ql[1][1], pB1h, acc);
                acc = MFMA16(qh[1][1], pB1m, acc);
                acc = MFMA16(qm[1][1], pB1h, acc);
                acc = MFMA16(qh[1][1], pB1h, acc);
                const int h = wave * 2 + 1;
                #pragma unroll
                for (int r = 0; r < 4; ++r) {
                    int i   = quad * 4 + r;
                    int rot = ((ln16 >> 2) + i + (i >> 2)) & 3;
                    Sb[h * 256 + i * 16 + rot * 4 + (ln16 & 3)] = acc[r];
                }
            }

            // ---- full prefetch of next tile (cross-row continuous):
            // K addr depends only on jt; next row starts at jt=0.
            {
                const int jt_next = (jt + 1 < jt_hi) ? jt + 1 : 0;
                const u32 jn = (u32)(jt_next * 16) * DH;
                pA0h = *(const bf16x8*)(k_hi + kbA + jn);
                pA0m = *(const bf16x8*)(k_mi + kbA + jn);
                pA0l = *(const bf16x8*)(k_lo + kbA + jn);
                pA1h = *(const bf16x8*)(k_hi + kbA + jn + 32u);
                pA1m = *(const bf16x8*)(k_mi + kbA + jn + 32u);
                pA1l = *(const bf16x8*)(k_lo + kbA + jn + 32u);
                pB0h = *(const bf16x8*)(k_hi + kbB + jn);
                pB0m = *(const bf16x8*)(k_mi + kbB + jn);
                pB0l = *(const bf16x8*)(k_lo + kbB + jn);
                pB1h = *(const bf16x8*)(k_hi + kbB + jn + 32u);
                pB1m = *(const bf16x8*)(k_mi + kbB + jn + 32u);
                pB1l = *(const bf16x8*)(k_lo + kbB + jn + 32u);
            }

            // ---- LDS handoff WITHOUT vmcnt drain ----
            asm volatile("s_waitcnt lgkmcnt(0)" ::: "memory");
            __builtin_amdgcn_s_barrier();
            __builtin_amdgcn_sched_barrier(0);   // pin: no mix-read hoisting

            // fused mix+scan for row (kk_r, ti_r), tj chunks {2*tjh, 2*tjh+1}
            const int jb = jt * 16;
            #pragma unroll
            for (int tc = 0; tc < 2; ++tc) {
                const int tjc = tjh * 2 + tc;
                const int rot = (tjc + ti_r + (ti_r >> 2)) & 3;
                const float* sp = Sb + ti_r * 16 + rot * 4;
                f32x4 m = {};
                #pragma unroll
                for (int h = 0; h < 16; ++h) {
                    float w  = pp[h * 16 + kk_r];             // broadcast b32
                    f32x4 s4 = *(const f32x4*)(sp + h * 256); // 4-way bcast b128
                    m += s4 * w;                              // v_pk_fma_f32 x2
                }
                const int jb2 = jb + tjc * 4;
                #pragma unroll
                for (int e = 0; e < 4; ++e) {
                    float c = m[e];
                    int j = jb2 + e;
                    if (j <= jlim && c > tv[7]) {
                        #pragma unroll
                        for (int t = 7; t >= 1; --t) {
                            if (c > tv[t - 1])      { tv[t] = tv[t - 1]; tx[t] = tx[t - 1]; }
                            else if (c > tv[t])     { tv[t] = c;         tx[t] = j; }
                        }
                        if (c > tv[0]) { tv[0] = c; tx[0] = j; }
                    }
                }
            }
            // no trailing barrier: next tile writes the other S buffer; the
            // per-tile barrier above orders reads(t) before writes(t+2).
        }

        // ---- row flush: merge tj-halves, write ws slot ----
        __syncthreads();                         // all scans for this row done
        if (tjh == 1) {
            #pragma unroll
            for (int t = 0; t < 8; ++t) {
                scr[srow * 8 + t]        = tv[t];
                scr[2048 + srow * 8 + t] = __int_as_float(tx[t]);
            }
        }
        __syncthreads();
        if (tjh == 0) {
            #pragma unroll
            for (int t2 = 0; t2 < 8; ++t2) {
                float c = scr[srow * 8 + t2];
                int   j = __float_as_int(scr[2048 + srow * 8 + t2]);
                if (c > tv[7]) {
                    #pragma unroll
                    for (int t = 7; t >= 1; --t) {
                        if (c > tv[t - 1])      { tv[t] = tv[t - 1]; tx[t] = tx[t - 1]; }
                        else if (c > tv[t])     { tv[t] = c;         tx[t] = j; }
                    }
                    if (c > tv[0]) { tv[0] = c; tx[0] = j; }
                }
            }
            size_t base = ((((size_t)b * HS + kk_r) * NN + i0 + ti_r) * JC + slot) * 8;
            #pragma unroll
            for (int t = 0; t < 8; ++t) {
                ws_val[base + t] = tv[t];
                ws_idx[base + t] = (u16)tx[t];
            }
        }

        g += nrow;
        ++iy;                                    // valid when row exhausted;
    }                                            // otherwise g==gend -> exit
}

// ---------------------------------------------------------------------------
// Phase 2: merge partial top-8s -> softmax -> sparse PV -> fused out-proj.
// (== R21: 512 threads, dh-split PV, 8-wave out-proj)
// ---------------------------------------------------------------------------
__global__ __launch_bounds__(512) void merge_pv_kernel(
    const u16* __restrict__ v_bf, const float* __restrict__ mem_v,
    const float* __restrict__ ws_val, const u16* __restrict__ ws_idx,
    const float* __restrict__ post, const u16* __restrict__ wot,
    const float* __restrict__ bo, float* __restrict__ out)
{
    __shared__ __align__(16) float fsm[13312];
    float* dotsm = fsm + 8704;     // [4096]: w park [0..2047], j park [2048..4095]
    float* pp2   = fsm + 13056;    // [256] post_proj
    u16*   arows = (u16*)fsm;      // [16][1032] bf16 (PV rows)

    const int tid = threadIdx.x;
    const int b   = blockIdx.y;
    const int i0  = blockIdx.x * 16;
    const int ntiles = blockIdx.x + 2;
    const int Srow0  = row_start(blockIdx.x);
    const int jc_cnt = blk_of(Srow0 + ntiles - 1) - blk_of(Srow0) + 1;

    if (tid < 256) pp2[tid] = post[tid];

    // ---- phase 1 (threads 0-255): top-8 merge + softmax -> dotsm ----
    if (tid < 256) {
        const int kk_r = tid & 15, ti_r = tid >> 4;

        float tv[8];
        int   tx[8];
        #pragma unroll
        for (int t = 0; t < 8; ++t) { tv[t] = -1e30f; tx[t] = 0; }

        size_t rbase = (((size_t)b * HS + kk_r) * NN + i0 + ti_r) * JC;
        for (int jc = 0; jc < jc_cnt; ++jc) {
            #pragma unroll
            for (int t2 = 0; t2 < 8; ++t2) {
                float c = ws_val[(rbase + jc) * 8 + t2];
                int   j = ws_idx[(rbase + jc) * 8 + t2];
                if (c > tv[7]) {
                    #pragma unroll
                    for (int t = 7; t >= 1; --t) {
                        if (c > tv[t - 1])      { tv[t] = tv[t - 1]; tx[t] = tx[t - 1]; }
                        else if (c > tv[t])     { tv[t] = c;         tx[t] = j; }
                    }
                    if (c > tv[0]) { tv[0] = c; tx[0] = j; }
                }
            }
        }

        float m = tv[0];
        float wv[8], wsum = 0.f;
        #pragma unroll
        for (int t = 0; t < 8; ++t) { wv[t] = __expf(tv[t] - m); wsum += wv[t]; }
        float inv = 1.f / wsum;

        #pragma unroll
        for (int t = 0; t < 8; ++t) {
            dotsm[(kk_r * 16 + ti_r) * 8 + t]        = wv[t] * inv;
            dotsm[2048 + (kk_r * 16 + ti_r) * 8 + t] = __int_as_float(tx[t]);
        }
    }
    __syncthreads();

    // ---- phase 2 PV: thread = (dh, ti_o, k2); dh splits the d-dimension ----
    {
        const int ti_o = (tid & 255) >> 4, k2 = tid & 15, dh = tid >> 8;
        float acc[32];
        #pragma unroll
        for (int d = 0; d < 32; ++d) acc[d] = 0.f;
        const u16*   vws_base  = v_bf + (size_t)(b * HS + k2) * NN * DH + dh * 32;
        const float* vmem_base = mem_v + (size_t)k2 * NM * DH + dh * 32;

        for (int kk = 0; kk < 16; ++kk) {
            float p2 = pp2[kk * 16 + k2];
            for (int t = 0; t < 8; ++t) {
                float w = dotsm[(kk * 16 + ti_o) * 8 + t] * p2;
                int j = __float_as_int(dotsm[2048 + (kk * 16 + ti_o) * 8 + t]);
                if (j < NM) {
                    const float* vr = vmem_base + (size_t)j * DH;
                    #pragma unroll
                    for (int r = 0; r < 8; ++r) {
                        float4 u = *(const float4*)&vr[r * 4];
                        acc[r * 4 + 0] += w * u.x; acc[r * 4 + 1] += w * u.y;
                        acc[r * 4 + 2] += w * u.z; acc[r * 4 + 3] += w * u.w;
                    }
                } else {
                    const uint4* vr = (const uint4*)(vws_base + (size_t)(j - NM) * DH);
                    #pragma unroll
                    for (int r = 0; r < 4; ++r) {
                        uint4 u = vr[r];
                        acc[r * 8 + 0] += w * lo16(u.x); acc[r * 8 + 1] += w * hi16(u.x);
                        acc[r * 8 + 2] += w * lo16(u.y); acc[r * 8 + 3] += w * hi16(u.y);
                        acc[r * 8 + 4] += w * lo16(u.z); acc[r * 8 + 5] += w * hi16(u.z);
                        acc[r * 8 + 6] += w * lo16(u.w); acc[r * 8 + 7] += w * hi16(u.w);
                    }
                }
            }
        }
        #pragma unroll
        for (int d = 0; d < 32; ++d) {
            float o = acc[d];
            o = (o == o) ? o : 1e4f;             // V-side NaN sentinel (diagnostic)
            arows[ti_o * 1032 + k2 * 64 + dh * 32 + d] = f2bf(o);
        }
    }
    __syncthreads();

    // ---- phase 3 out-proj: 8 waves, n = (t8*8 + wave)*16 + ln16 ----
    const int wave = tid >> 6, lane = tid & 63;
    const int ln16 = lane & 15, quad = lane >> 4;

    f32x4 oacc[8];
    #pragma unroll
    for (int t = 0; t < 8; ++t) {
        float bv = bo[(t * 8 + wave) * 16 + ln16];
        oacc[t][0] = bv; oacc[t][1] = bv; oacc[t][2] = bv; oacc[t][3] = bv;
    }

    for (int k0 = 0; k0 < 1024; k0 += 32) {
        bf16x8 af = *(const bf16x8*)&arows[ln16 * 1032 + k0 + quad * 8];
        #pragma unroll
        for (int t = 0; t < 8; ++t) {
            const int n = (t * 8 + wave) * 16 + ln16;
            bf16x8 bf_ = *(const bf16x8*)&wot[(size_t)n * 1024 + k0 + quad * 8];
            oacc[t] = MFMA16(af, bf_, oacc[t]);
        }
    }

    #pragma unroll
    for (int t = 0; t < 8; ++t) {
        const int n = (t * 8 + wave) * 16 + ln16;
        #pragma unroll
        for (int r = 0; r < 4; ++r) {
            int row = quad * 4 + r;
            out[(size_t)(b * NN + i0 + row) * DIM + n] = oacc[t][r];
        }
    }
}

// ---------------------------------------------------------------------------
extern "C" void kernel_launch(void* const* d_in, const int* in_sizes, int n_in,
                              void* d_out, int out_size, void* d_ws, size_t ws_size,
                              hipStream_t stream)
{
    (void)in_sizes; (void)n_in; (void)out_size; (void)ws_size;
    const float* x     = (const float*)d_in[0];
    const float* Wq    = (const float*)d_in[1];
    const float* Wk    = (const float*)d_in[2];
    const float* Wv    = (const float*)d_in[3];
    const float* pre   = (const float*)d_in[4];
    const float* post  = (const float*)d_in[5];
    const float* mem_k = (const float*)d_in[6];
    const float* mem_v = (const float*)d_in[7];
    const float* Wo    = (const float*)d_in[8];
    const float* bo    = (const float*)d_in[9];

    // workspace (51.6 MB total, < 54.6 proven):
    //   K splits 3x bf16 [2][16][2064][64]            = 25.36 MB
    //   V bf16 [2][16][2048][64]                      =  8.39 MB
    //   partial top-8 val f32 [2][16][2048][JC=5][8]  = 10.49 MB
    //   partial top-8 idx u16                          =  5.24 MB
    //   WoT bf16 [1024][1024]                         =  2.10 MB
    u16*   k_sp   = (u16*)d_ws;
    u16*   v_bf   = k_sp + 3 * SPLITSZ;
    float* ws_val = (float*)(v_bf + (size_t)BB * HS * NN * DH);
    u16*   ws_idx = (u16*)(ws_val + (size_t)BB * HS * NN * JC * 8);
    u16*   wot    = ws_idx + (size_t)BB * HS * NN * JC * 8;
    float* q_tmp  = (float*)d_out;                           // Q f32 [b*n][1024]

    prep_mem_kernel<<<128, 256, 0, stream>>>(mem_k, k_sp);
    prep_wot_kernel<<<1024, 256, 0, stream>>>(Wo, wot);

    dim3 gg(32, 16);
    gemm_kernel<<<gg, 256, 0, stream>>>(x, Wq, nullptr, q_tmp, 1);  // Q -> d_out
    gemm_kernel<<<gg, 256, 0, stream>>>(x, Wk, k_sp, nullptr, 2);   // K -> split planes
    gemm_kernel<<<gg, 256, 0, stream>>>(x, Wv, v_bf, nullptr, 0);   // V -> bf16 ws (4-pass)

    // uniform tile-partition grid: 512 blocks = exactly 2 resident per CU
    score_topk_kernel<<<512, 512, 0, stream>>>(k_sp, k_sp + SPLITSZ,
                                               k_sp + 2 * SPLITSZ,
                                               (const float*)d_out,
                                               pre, ws_val, ws_idx);

    dim3 ga(128, 2);
    merge_pv_kernel<<<ga, 512, 0, stream>>>(v_bf, mem_v, ws_val, ws_idx,
                                            post, wot, bo, (float*)d_out);
}